// Round 6
// baseline (1002.250 us; speedup 1.0000x reference)
//
#include <hip/hip_runtime.h>
#include <math.h>

#define N_USERS 100000
#define N_ITEMS 50000
#define NE      2000000
#define NB      100000
#define H       64
#define BN_EPS  1e-5f
#define NXCD    8
#define U_LOC   (N_USERS / NXCD)          // 12500 users per partition
#define I_LOC   (N_ITEMS / NXCD)          // 6250 items per partition
#define HSLOTS  (U_LOC + I_LOC)           // 18750 ints = 75 KB LDS
#define S_SLICES 64                        // edge slices per partition
#define NBLK_CSR (NXCD * S_SLICES)         // 512 blocks
#define E_SLICE  (NE / S_SLICES)           // 31250 edges per slice

static __device__ __forceinline__ int rfl(int x) { return __builtin_amdgcn_readfirstlane(x); }

// ---------------- projection: Y[N,64] = X[N,K] @ W[K,64] + b ----------------
// 4 waves split K (slice in float4 VGPRs, lane = out channel). One sequential
// row stream per wave (R3 lesson: interleaved streams -> 4.7x overfetch).
// R4 lesson: VGPR_Count=40 showed the compiler re-streamed W from L2 per row;
// __launch_bounds__(256,4) (128-VGPR cap) + float4 weights force residency.
template<int K>
__global__ __launch_bounds__(256, 4) void proj_kernel(
    const float* __restrict__ X, const float* __restrict__ W,
    const float* __restrict__ bias, float* __restrict__ Y, int nrows) {
  constexpr int SL  = K / 4;    // K-slice per wave
  constexpr int SL4 = SL / 4;   // float4 chunks (16 for K=256, 8 for K=128)
  const int lane = threadIdx.x & 63;
  const int wid  = rfl((int)(threadIdx.x >> 6));
  const int k0   = wid * SL;
  float4 w[SL4];
#pragma unroll
  for (int k = 0; k < SL4; k++) {
    const int kk = k0 + k * 4;
    w[k].x = W[(kk + 0) * H + lane];
    w[k].y = W[(kk + 1) * H + lane];
    w[k].z = W[(kk + 2) * H + lane];
    w[k].w = W[(kk + 3) * H + lane];
  }
  const float bv = bias[lane];
  __shared__ float part[2][4][2][64];   // [parity][wave][row][chan]
  int par = 0;
  for (int rb = blockIdx.x * 2; rb < nrows; rb += gridDim.x * 2, par ^= 1) {
#pragma unroll
    for (int row = 0; row < 2; row++) {
      const float4* xr =
          reinterpret_cast<const float4*>(X + (size_t)(rb + row) * K + k0);
      float a0 = 0.f, a1 = 0.f, a2 = 0.f, a3 = 0.f;
#pragma unroll
      for (int k = 0; k < SL4; k++) {
        const float4 xv = xr[k];
        a0 = fmaf(xv.x, w[k].x, a0);
        a1 = fmaf(xv.y, w[k].y, a1);
        a2 = fmaf(xv.z, w[k].z, a2);
        a3 = fmaf(xv.w, w[k].w, a3);
      }
      part[par][wid][row][lane] = (a0 + a1) + (a2 + a3);
    }
    __syncthreads();
    if (wid < 2) {
      Y[(size_t)(rb + wid) * H + lane] =
          part[par][0][wid][lane] + part[par][1][wid][lane] +
          part[par][2][wid][lane] + part[par][3][wid][lane] + bv;
    }
    // double-buffered part[] -> no trailing barrier needed.
  }
}

// ---------------- CSR build, atomic-free counting sort ----------------
__global__ __launch_bounds__(256) void hist2_kernel(
    const int* __restrict__ src, const int* __restrict__ dst,
    int* __restrict__ PH) {
  __shared__ int h[HSLOTS];
  const int x = blockIdx.x & (NXCD - 1);
  const int s = blockIdx.x >> 3;
  for (int i = threadIdx.x; i < HSLOTS; i += 256) h[i] = 0;
  __syncthreads();
  const int uLo = x * U_LOC, iLo = x * I_LOC;
  const int e0 = s * E_SLICE;
  for (int e = e0 + threadIdx.x; e < e0 + E_SLICE; e += 256) {
    const int u  = __builtin_nontemporal_load(&src[e]);
    const int it = __builtin_nontemporal_load(&dst[e]);
    const int ul = u - uLo, il = it - iLo;
    if ((unsigned)ul < (unsigned)U_LOC) atomicAdd(&h[ul], 1);
    if ((unsigned)il < (unsigned)I_LOC) atomicAdd(&h[U_LOC + il], 1);
  }
  __syncthreads();
  int* out = PH + (size_t)blockIdx.x * HSLOTS;
  for (int i = threadIdx.x; i < HSLOTS; i += 256) out[i] = h[i];
}

__global__ __launch_bounds__(256) void combine_kernel(
    int* __restrict__ PH, int* __restrict__ cntU, int* __restrict__ cntI) {
  const int g = blockIdx.x * 256 + threadIdx.x;
  if (g >= NXCD * HSLOTS) return;
  const int x = g / HSLOTS;
  const int n = g - x * HSLOTS;
  int* p = PH + (size_t)x * HSLOTS + n;
  int run = 0;
#pragma unroll 4
  for (int s = 0; s < S_SLICES; s++) {
    int* q = p + (size_t)s * (NXCD * HSLOTS);
    const int v = *q;
    *q = run;
    run += v;
  }
  if (n < U_LOC) cntU[x * U_LOC + n] = run;
  else           cntI[x * I_LOC + (n - U_LOC)] = run;
}

// single-block exclusive scan: 8 elems/thread, wave shfl-scan + LDS combine
__global__ __launch_bounds__(1024) void scan_kernel(
    const int* __restrict__ cnt, int* __restrict__ row, int n) {
  __shared__ int wtot[16];
  __shared__ int carry_s;
  const int tid = threadIdx.x;
  const int lane = tid & 63, wv = tid >> 6;
  if (tid == 0) { carry_s = 0; row[0] = 0; }
  __syncthreads();
  for (int base = 0; base < n; base += 8192) {
    const int i0 = base + tid * 8;
    int v, sacc[8];
    int run = 0;
#pragma unroll
    for (int k = 0; k < 8; k++) {
      v = (i0 + k < n) ? cnt[i0 + k] : 0;
      run += v;
      sacc[k] = run;
    }
    int x = run;
#pragma unroll
    for (int off = 1; off < 64; off <<= 1) {
      const int y = __shfl_up(x, off);
      if (lane >= off) x += y;
    }
    if (lane == 63) wtot[wv] = x;
    __syncthreads();
    int woff = 0;
#pragma unroll
    for (int k = 0; k < 16; k++) woff += (k < wv) ? wtot[k] : 0;
    const int thr_excl = (x - run) + woff + carry_s;
#pragma unroll
    for (int k = 0; k < 8; k++)
      if (i0 + k < n) row[i0 + k + 1] = thr_excl + sacc[k];
    __syncthreads();
    if (tid == 1023) carry_s = thr_excl + run;
    __syncthreads();
  }
}

__global__ __launch_bounds__(256) void scatter2_kernel(
    const int* __restrict__ src, const int* __restrict__ dst,
    const int* __restrict__ PH, const int* __restrict__ rowU,
    const int* __restrict__ rowI, int* __restrict__ adjU,
    int* __restrict__ adjI) {
  __shared__ int pos[HSLOTS];
  const int x = blockIdx.x & (NXCD - 1);
  const int s = blockIdx.x >> 3;
  const int uLo = x * U_LOC, iLo = x * I_LOC;
  const int* pre = PH + (size_t)blockIdx.x * HSLOTS;
  for (int i = threadIdx.x; i < U_LOC; i += 256)
    pos[i] = rowU[uLo + i] + pre[i];
  for (int i = threadIdx.x; i < I_LOC; i += 256)
    pos[U_LOC + i] = rowI[iLo + i] + pre[U_LOC + i];
  __syncthreads();
  const int e0 = s * E_SLICE;
  for (int e = e0 + threadIdx.x; e < e0 + E_SLICE; e += 256) {
    const int u  = __builtin_nontemporal_load(&src[e]);
    const int it = __builtin_nontemporal_load(&dst[e]);
    const int ul = u - uLo, il = it - iLo;
    if ((unsigned)ul < (unsigned)U_LOC) {
      const int p = atomicAdd(&pos[ul], 1);
      adjU[p] = it;
    }
    if ((unsigned)il < (unsigned)I_LOC) {
      const int p = atomicAdd(&pos[U_LOC + il], 1);
      adjI[p] = u;
    }
  }
}

// ---------------- aggregations: one wave per segment, lane = channel ----------------
__global__ __launch_bounds__(256) void agg_max_kernel(
    const float* __restrict__ feat, const int* __restrict__ rowptr,
    const int* __restrict__ adj, float* __restrict__ out, int nseg) {
  const int lane = threadIdx.x & 63;
  const int wid  = rfl((int)(threadIdx.x >> 6));
  for (int s = blockIdx.x * 4 + wid; s < nseg; s += gridDim.x * 4) {
    const int beg = rowptr[s], end = rowptr[s + 1];
    float m0 = -INFINITY, m1 = -INFINITY, m2 = -INFINITY, m3 = -INFINITY;
    int j = beg;
    for (; j + 4 <= end; j += 4) {
      const int n0 = adj[j], n1 = adj[j + 1], n2 = adj[j + 2], n3 = adj[j + 3];
      m0 = fmaxf(m0, feat[(size_t)n0 * H + lane]);
      m1 = fmaxf(m1, feat[(size_t)n1 * H + lane]);
      m2 = fmaxf(m2, feat[(size_t)n2 * H + lane]);
      m3 = fmaxf(m3, feat[(size_t)n3 * H + lane]);
    }
    for (; j < end; j++) m0 = fmaxf(m0, feat[(size_t)adj[j] * H + lane]);
    const float m = fmaxf(fmaxf(m0, m1), fmaxf(m2, m3));
    out[(size_t)s * H + lane] = (end > beg) ? m : 0.f;  // empty segment -> 0 (PyG)
  }
}

__global__ __launch_bounds__(256) void agg_mean_kernel(
    const float* __restrict__ feat, const int* __restrict__ rowptr,
    const int* __restrict__ adj, float* __restrict__ out, int nseg) {
  const int lane = threadIdx.x & 63;
  const int wid  = rfl((int)(threadIdx.x >> 6));
  for (int s = blockIdx.x * 4 + wid; s < nseg; s += gridDim.x * 4) {
    const int beg = rowptr[s], end = rowptr[s + 1];
    float a0 = 0.f, a1 = 0.f, a2 = 0.f, a3 = 0.f;
    int j = beg;
    for (; j + 4 <= end; j += 4) {
      const int n0 = adj[j], n1 = adj[j + 1], n2 = adj[j + 2], n3 = adj[j + 3];
      a0 += feat[(size_t)n0 * H + lane];
      a1 += feat[(size_t)n1 * H + lane];
      a2 += feat[(size_t)n2 * H + lane];
      a3 += feat[(size_t)n3 * H + lane];
    }
    for (; j < end; j++) a0 += feat[(size_t)adj[j] * H + lane];
    const float inv = 1.f / (float)((end - beg) > 1 ? (end - beg) : 1);
    out[(size_t)s * H + lane] = ((a0 + a1) + (a2 + a3)) * inv;
  }
}

// ---------------- fused conv: Y = relu(BN(AGG@Wl + bl + XS@Wr)) ----------------
// One row per wave per iteration, 128 weight floats resident as float4[32]
// (launch_bounds(256,2) -> 256-VGPR cap), 4 split accumulators, no barriers.
__global__ __launch_bounds__(256, 2) void conv_kernel(
    const float* __restrict__ AGG, const float* __restrict__ XS,
    const float* __restrict__ Wl, const float* __restrict__ bl,
    const float* __restrict__ Wr, const float* __restrict__ gm,
    const float* __restrict__ bt, const float* __restrict__ mu,
    const float* __restrict__ vr, float* __restrict__ Y, int nrows) {
  const int lane = threadIdx.x & 63;
  const int wid  = rfl((int)(threadIdx.x >> 6));
  float4 wl[16], wr[16];
#pragma unroll
  for (int k = 0; k < 16; k++) {
    wl[k].x = Wl[(k * 4 + 0) * 64 + lane];
    wl[k].y = Wl[(k * 4 + 1) * 64 + lane];
    wl[k].z = Wl[(k * 4 + 2) * 64 + lane];
    wl[k].w = Wl[(k * 4 + 3) * 64 + lane];
  }
#pragma unroll
  for (int k = 0; k < 16; k++) {
    wr[k].x = Wr[(k * 4 + 0) * 64 + lane];
    wr[k].y = Wr[(k * 4 + 1) * 64 + lane];
    wr[k].z = Wr[(k * 4 + 2) * 64 + lane];
    wr[k].w = Wr[(k * 4 + 3) * 64 + lane];
  }
  const float s = gm[lane] * rsqrtf(vr[lane] + BN_EPS);
  const float C = (bl[lane] - mu[lane]) * s + bt[lane];
  for (int r = blockIdx.x * 4 + wid; r < nrows; r += gridDim.x * 4) {
    const float4* a = reinterpret_cast<const float4*>(AGG + (size_t)r * 64);
    const float4* x = reinterpret_cast<const float4*>(XS + (size_t)r * 64);
    float c0 = 0.f, c1 = 0.f, c2 = 0.f, c3 = 0.f;
#pragma unroll
    for (int k = 0; k < 16; k++) {
      const float4 av = a[k];
      c0 = fmaf(av.x, wl[k].x, c0);
      c1 = fmaf(av.y, wl[k].y, c1);
      c2 = fmaf(av.z, wl[k].z, c2);
      c3 = fmaf(av.w, wl[k].w, c3);
    }
#pragma unroll
    for (int k = 0; k < 16; k++) {
      const float4 xv = x[k];
      c0 = fmaf(xv.x, wr[k].x, c0);
      c1 = fmaf(xv.y, wr[k].y, c1);
      c2 = fmaf(xv.z, wr[k].z, c2);
      c3 = fmaf(xv.w, wr[k].w, c3);
    }
    const float acc = (c0 + c1) + (c2 + c3);
    Y[(size_t)r * 64 + lane] = fmaxf(fmaf(acc, s, C), 0.f);
  }
}

// ---------------- head ----------------
__global__ __launch_bounds__(256, 2) void head_kernel(
    const float* __restrict__ ux, const float* __restrict__ ix,
    const int* __restrict__ eliU, const int* __restrict__ eliI,
    const float* __restrict__ W1, const float* __restrict__ b1,
    const float* __restrict__ W2, const float* __restrict__ b2,
    float* __restrict__ out) {
  const int lane = threadIdx.x & 63;
  const int wid  = rfl((int)(threadIdx.x >> 6));
  float4 w1[32];
#pragma unroll
  for (int k = 0; k < 32; k++) {
    w1[k].x = W1[(k * 4 + 0) * 64 + lane];
    w1[k].y = W1[(k * 4 + 1) * 64 + lane];
    w1[k].z = W1[(k * 4 + 2) * 64 + lane];
    w1[k].w = W1[(k * 4 + 3) * 64 + lane];
  }
  const float b1v = b1[lane];
  const float w2a = W2[lane * 4 + 0], w2b = W2[lane * 4 + 1];
  const float w2c = W2[lane * 4 + 2], w2d = W2[lane * 4 + 3];
  const float cb0 = b2[0], cb1 = b2[1], cb2 = b2[2], cb3 = b2[3];
  for (int b = blockIdx.x * 4 + wid; b < NB; b += gridDim.x * 4) {
    const int u = eliU[b], it = eliI[b];
    const float4* xu = reinterpret_cast<const float4*>(ux + (size_t)u * 64);
    const float4* xi = reinterpret_cast<const float4*>(ix + (size_t)it * 64);
    float a0 = b1v, a1 = 0.f, a2 = 0.f, a3 = 0.f;
#pragma unroll
    for (int k = 0; k < 16; k++) {
      const float4 xv = xu[k];
      a0 = fmaf(xv.x, w1[k].x, a0);
      a1 = fmaf(xv.y, w1[k].y, a1);
      a2 = fmaf(xv.z, w1[k].z, a2);
      a3 = fmaf(xv.w, w1[k].w, a3);
    }
#pragma unroll
    for (int k = 0; k < 16; k++) {
      const float4 xv = xi[k];
      a0 = fmaf(xv.x, w1[16 + k].x, a0);
      a1 = fmaf(xv.y, w1[16 + k].y, a1);
      a2 = fmaf(xv.z, w1[16 + k].z, a2);
      a3 = fmaf(xv.w, w1[16 + k].w, a3);
    }
    const float h = fmaxf((a0 + a1) + (a2 + a3), 0.f);
    float o0 = h * w2a, o1 = h * w2b, o2 = h * w2c, o3 = h * w2d;
#pragma unroll
    for (int off = 32; off; off >>= 1) {
      o0 += __shfl_down(o0, off);
      o1 += __shfl_down(o1, off);
      o2 += __shfl_down(o2, off);
      o3 += __shfl_down(o3, off);
    }
    if (lane == 0) {
      float4 o = { o0 + cb0, o1 + cb1, o2 + cb2, o3 + cb3 };
      *reinterpret_cast<float4*>(out + (size_t)b * 4) = o;
    }
  }
}

// ---------------- launch ----------------
extern "C" void kernel_launch(void* const* d_in, const int* in_sizes, int n_in,
                              void* d_out, int out_size, void* d_ws, size_t ws_size,
                              hipStream_t stream) {
  const float* userF = (const float*)d_in[0];
  const float* itemF = (const float*)d_in[1];
  const int*   src   = (const int*)d_in[2];
  const int*   dst   = src + NE;
  const int*   eliU  = (const int*)d_in[3];
  const int*   eliI  = eliU + NB;
  const float* upW = (const float*)d_in[4],  *upb = (const float*)d_in[5];
  const float* ipW = (const float*)d_in[6],  *ipb = (const float*)d_in[7];
  const float* ulW = (const float*)d_in[8],  *ulb = (const float*)d_in[9];
  const float* urW = (const float*)d_in[10];
  const float* ilW = (const float*)d_in[11], *ilb = (const float*)d_in[12];
  const float* irW = (const float*)d_in[13];
  const float* ug  = (const float*)d_in[14], *ube = (const float*)d_in[15];
  const float* um  = (const float*)d_in[16], *uv  = (const float*)d_in[17];
  const float* ig  = (const float*)d_in[18], *ibe = (const float*)d_in[19];
  const float* im  = (const float*)d_in[20], *iv  = (const float*)d_in[21];
  const float* f1W = (const float*)d_in[22], *f1b = (const float*)d_in[23];
  const float* f2W = (const float*)d_in[24], *f2b = (const float*)d_in[25];
  float* outp = (float*)d_out;

  char* p = (char*)d_ws;
  auto alloc = [&](size_t bytes) {
    char* r = p;
    p += (bytes + 255) & ~(size_t)255;
    return r;
  };
  float* ux0  = (float*)alloc((size_t)N_USERS * H * 4);
  float* ux1  = (float*)alloc((size_t)N_USERS * H * 4);
  float* ix0  = (float*)alloc((size_t)N_ITEMS * H * 4);
  float* ix1  = (float*)alloc((size_t)N_ITEMS * H * 4);
  float* agU  = (float*)alloc((size_t)N_USERS * H * 4);   // 25.6 MB
  float* agI  = (float*)alloc((size_t)N_ITEMS * H * 4);   // 12.8 MB (contiguous after agU)
  int*   rowU = (int*)alloc((size_t)(N_USERS + 1) * 4);
  int*   rowI = (int*)alloc((size_t)(N_ITEMS + 1) * 4);
  int*   cntU = (int*)alloc((size_t)N_USERS * 4);
  int*   cntI = (int*)alloc((size_t)N_ITEMS * 4);
  int*   adjU = (int*)alloc((size_t)NE * 4);
  int*   adjI = (int*)alloc((size_t)NE * 4);
  // PH (512 x 18750 ints = 38.4 MB) aliases agU+agI (dead until agg phase).
  int*   PH   = (int*)agU;

  const int G = 2048, T = 256;
  proj_kernel<256><<<G, T, 0, stream>>>(userF, upW, upb, ux0, N_USERS);
  proj_kernel<128><<<G, T, 0, stream>>>(itemF, ipW, ipb, ix0, N_ITEMS);
  hist2_kernel<<<NBLK_CSR, T, 0, stream>>>(src, dst, PH);
  combine_kernel<<<(NXCD * HSLOTS + 255) / 256, T, 0, stream>>>(PH, cntU, cntI);
  scan_kernel<<<1, 1024, 0, stream>>>(cntU, rowU, N_USERS);
  scan_kernel<<<1, 1024, 0, stream>>>(cntI, rowI, N_ITEMS);
  scatter2_kernel<<<NBLK_CSR, T, 0, stream>>>(src, dst, PH, rowU, rowI, adjU, adjI);

  const float* uin = ux0;
  const float* iin = ix0;
  float* uout = ux1;
  float* iout = ix1;
  for (int l = 0; l < 2; l++) {
    agg_max_kernel<<<G, T, 0, stream>>>(iin, rowU, adjU, agU, N_USERS);
    conv_kernel<<<G, T, 0, stream>>>(agU, uin, ulW + l * 4096, ulb + l * 64,
                                     urW + l * 4096, ug + l * 64, ube + l * 64,
                                     um + l * 64, uv + l * 64, uout, N_USERS);
    agg_mean_kernel<<<G, T, 0, stream>>>(uin, rowI, adjI, agI, N_ITEMS);
    conv_kernel<<<G, T, 0, stream>>>(agI, iin, ilW + l * 4096, ilb + l * 64,
                                     irW + l * 4096, ig + l * 64, ibe + l * 64,
                                     im + l * 64, iv + l * 64, iout, N_ITEMS);
    const float* t;
    t = uin; uin = uout; uout = (float*)t;
    t = iin; iin = iout; iout = (float*)t;
  }
  head_kernel<<<G, T, 0, stream>>>(uin, iin, eliU, eliI, f1W, f1b, f2W, f2b, outp);
}

// Round 7
// 708.983 us; speedup vs baseline: 1.4136x; 1.4136x over previous
//
#include <hip/hip_runtime.h>
#include <math.h>

#define N_USERS 100000
#define N_ITEMS 50000
#define NE      2000000
#define NB      100000
#define H       64
#define BN_EPS  1e-5f
#define NXCD    8
#define U_LOC   (N_USERS / NXCD)
#define I_LOC   (N_ITEMS / NXCD)
#define HSLOTS  (U_LOC + I_LOC)
#define S_SLICES 64
#define NBLK_CSR (NXCD * S_SLICES)
#define E_SLICE  (NE / S_SLICES)

typedef __attribute__((ext_vector_type(8))) short bf16x8;
typedef __attribute__((ext_vector_type(4))) float f32x4;

static __device__ __forceinline__ int rfl(int x) { return __builtin_amdgcn_readfirstlane(x); }

static __device__ __forceinline__ unsigned short f2bf(float f) {   // RTNE
  union { float f; unsigned u; } v; v.f = f;
  const unsigned r = v.u + 0x7fffu + ((v.u >> 16) & 1u);
  return (unsigned short)(r >> 16);
}
static __device__ __forceinline__ float bf2f(unsigned short h) {
  union { unsigned u; float f; } v; v.u = (unsigned)h << 16;
  return v.f;
}

// ---------------- weight pre-pack into MFMA fragment order ----------------
// frag table layout per kstep-block: [ct(4)][lane(64)][j(8)] bf16 (2048 shorts)
// B-frag for mfma_16x16x32: lane l supplies B[k=(l>>4)*8+j][col=l&15].
// blocks 0..7: user proj (K=256); 8..11: item proj (K=128);
// 12..27: conv tables t={u.l0,u.l1,i.l0,i.l1}, 4 ksteps each
// (kstep 0,1 from lin_l; kstep 2,3 from lin_r; all W are [K][64] row-major).
__global__ __launch_bounds__(256) void pack_kernel(
    const float* __restrict__ upW, const float* __restrict__ ipW,
    const float* __restrict__ ulW, const float* __restrict__ urW,
    const float* __restrict__ ilW, const float* __restrict__ irW,
    unsigned short* __restrict__ dst) {
  const int b = blockIdx.x;
  const int ct = threadIdx.x >> 6, lane = threadIdx.x & 63;
  const float* src;
  int krow0;
  if (b < 8)       { src = upW; krow0 = b * 32; }
  else if (b < 12) { src = ipW; krow0 = (b - 8) * 32; }
  else {
    const int idx = b - 12, t = idx >> 2, ks = idx & 3;
    const int layer = t & 1;
    const float* Wl = (t < 2) ? ulW : ilW;
    const float* Wr = (t < 2) ? urW : irW;
    src = ((ks < 2) ? Wl : Wr) + layer * 4096;
    krow0 = ((ks < 2) ? ks : ks - 2) * 32;
  }
  unsigned short* out = dst + (size_t)b * 2048 + ((size_t)ct * 64 + lane) * 8;
  const int col = ct * 16 + (lane & 15);
  const int kr = krow0 + (lane >> 4) * 8;
#pragma unroll
  for (int j = 0; j < 8; j++) out[j] = f2bf(src[(kr + j) * 64 + col]);
}

// ---------------- proj: Y[N,64] = bf16(X[N,K] @ W + b) via MFMA ----------------
// wave owns 16 rows x 64 cols; A from global f32 (cvt), B from packed table.
template<int K>
__global__ __launch_bounds__(256) void proj_mfma(
    const float* __restrict__ X, const unsigned short* __restrict__ Wf,
    const float* __restrict__ bias, unsigned short* __restrict__ Y, int nrows) {
  const int lane = threadIdx.x & 63;
  const int wave = rfl((int)(threadIdx.x >> 6));
  const int r0 = (blockIdx.x * 4 + wave) * 16;
  if (r0 >= nrows) return;
  const int arow = r0 + (lane & 15);
  const int ar = arow < nrows ? arow : nrows - 1;   // clamp; stores predicated
  const int k0 = (lane >> 4) * 8;
  f32x4 acc[4] = {};
#pragma unroll
  for (int ks = 0; ks < K / 32; ks++) {
    const float* xp = X + (size_t)ar * K + ks * 32 + k0;
    const float4 xa = *reinterpret_cast<const float4*>(xp);
    const float4 xb = *reinterpret_cast<const float4*>(xp + 4);
    bf16x8 af;
    af[0] = f2bf(xa.x); af[1] = f2bf(xa.y); af[2] = f2bf(xa.z); af[3] = f2bf(xa.w);
    af[4] = f2bf(xb.x); af[5] = f2bf(xb.y); af[6] = f2bf(xb.z); af[7] = f2bf(xb.w);
#pragma unroll
    for (int ct = 0; ct < 4; ct++) {
      const bf16x8 bfr = *reinterpret_cast<const bf16x8*>(
          Wf + ((size_t)(ks * 4 + ct) * 64 + lane) * 8);
      acc[ct] = __builtin_amdgcn_mfma_f32_16x16x32_bf16(af, bfr, acc[ct], 0, 0, 0);
    }
  }
  const int orow0 = r0 + (lane >> 4) * 4;
#pragma unroll
  for (int ct = 0; ct < 4; ct++) {
    const int col = ct * 16 + (lane & 15);
    const float bv = bias[col];
#pragma unroll
    for (int i = 0; i < 4; i++) {
      const int r = orow0 + i;
      if (r < nrows) Y[(size_t)r * 64 + col] = f2bf(acc[ct][i] + bv);
    }
  }
}

// ---------------- conv: Y = bf16(relu(BN([AGG|XS] @ [Wl;Wr] + bl))) ----------------
__global__ __launch_bounds__(256) void conv_mfma(
    const unsigned short* __restrict__ AGG, const unsigned short* __restrict__ XS,
    const unsigned short* __restrict__ Wf, const float* __restrict__ bl,
    const float* __restrict__ gm, const float* __restrict__ bt,
    const float* __restrict__ mu, const float* __restrict__ vr,
    unsigned short* __restrict__ Y, int nrows) {
  const int lane = threadIdx.x & 63;
  const int wave = rfl((int)(threadIdx.x >> 6));
  const int r0 = (blockIdx.x * 4 + wave) * 16;
  if (r0 >= nrows) return;
  const int arow = r0 + (lane & 15);
  const int ar = arow < nrows ? arow : nrows - 1;
  const int k0 = (lane >> 4) * 8;
  f32x4 acc[4] = {};
#pragma unroll
  for (int ks = 0; ks < 4; ks++) {
    const unsigned short* ap =
        (ks < 2 ? AGG : XS) + (size_t)ar * 64 + (ks & 1) * 32 + k0;
    const bf16x8 af = *reinterpret_cast<const bf16x8*>(ap);
#pragma unroll
    for (int ct = 0; ct < 4; ct++) {
      const bf16x8 bfr = *reinterpret_cast<const bf16x8*>(
          Wf + ((size_t)(ks * 4 + ct) * 64 + lane) * 8);
      acc[ct] = __builtin_amdgcn_mfma_f32_16x16x32_bf16(af, bfr, acc[ct], 0, 0, 0);
    }
  }
  const int orow0 = r0 + (lane >> 4) * 4;
#pragma unroll
  for (int ct = 0; ct < 4; ct++) {
    const int col = ct * 16 + (lane & 15);
    const float s = gm[col] * rsqrtf(vr[col] + BN_EPS);
    const float C = (bl[col] - mu[col]) * s + bt[col];
#pragma unroll
    for (int i = 0; i < 4; i++) {
      const int r = orow0 + i;
      if (r < nrows)
        Y[(size_t)r * 64 + col] = f2bf(fmaxf(fmaf(acc[ct][i], s, C), 0.f));
    }
  }
}

// ---------------- CSR build (unchanged from R5) ----------------
__global__ __launch_bounds__(256) void hist2_kernel(
    const int* __restrict__ src, const int* __restrict__ dst,
    int* __restrict__ PH) {
  __shared__ int h[HSLOTS];
  const int x = blockIdx.x & (NXCD - 1);
  const int s = blockIdx.x >> 3;
  for (int i = threadIdx.x; i < HSLOTS; i += 256) h[i] = 0;
  __syncthreads();
  const int uLo = x * U_LOC, iLo = x * I_LOC;
  const int e0 = s * E_SLICE;
  for (int e = e0 + threadIdx.x; e < e0 + E_SLICE; e += 256) {
    const int u  = __builtin_nontemporal_load(&src[e]);
    const int it = __builtin_nontemporal_load(&dst[e]);
    const int ul = u - uLo, il = it - iLo;
    if ((unsigned)ul < (unsigned)U_LOC) atomicAdd(&h[ul], 1);
    if ((unsigned)il < (unsigned)I_LOC) atomicAdd(&h[U_LOC + il], 1);
  }
  __syncthreads();
  int* out = PH + (size_t)blockIdx.x * HSLOTS;
  for (int i = threadIdx.x; i < HSLOTS; i += 256) out[i] = h[i];
}

__global__ __launch_bounds__(256) void combine_kernel(
    int* __restrict__ PH, int* __restrict__ cntU, int* __restrict__ cntI) {
  const int g = blockIdx.x * 256 + threadIdx.x;
  if (g >= NXCD * HSLOTS) return;
  const int x = g / HSLOTS;
  const int n = g - x * HSLOTS;
  int* p = PH + (size_t)x * HSLOTS + n;
  int run = 0;
#pragma unroll 4
  for (int s = 0; s < S_SLICES; s++) {
    int* q = p + (size_t)s * (NXCD * HSLOTS);
    const int v = *q;
    *q = run;
    run += v;
  }
  if (n < U_LOC) cntU[x * U_LOC + n] = run;
  else           cntI[x * I_LOC + (n - U_LOC)] = run;
}

__global__ __launch_bounds__(1024) void scan_kernel(
    const int* __restrict__ cnt, int* __restrict__ row, int n) {
  __shared__ int wtot[16];
  __shared__ int carry_s;
  const int tid = threadIdx.x;
  const int lane = tid & 63, wv = tid >> 6;
  if (tid == 0) { carry_s = 0; row[0] = 0; }
  __syncthreads();
  for (int base = 0; base < n; base += 8192) {
    const int i0 = base + tid * 8;
    int v, sacc[8];
    int run = 0;
#pragma unroll
    for (int k = 0; k < 8; k++) {
      v = (i0 + k < n) ? cnt[i0 + k] : 0;
      run += v;
      sacc[k] = run;
    }
    int x = run;
#pragma unroll
    for (int off = 1; off < 64; off <<= 1) {
      const int y = __shfl_up(x, off);
      if (lane >= off) x += y;
    }
    if (lane == 63) wtot[wv] = x;
    __syncthreads();
    int woff = 0;
#pragma unroll
    for (int k = 0; k < 16; k++) woff += (k < wv) ? wtot[k] : 0;
    const int thr_excl = (x - run) + woff + carry_s;
#pragma unroll
    for (int k = 0; k < 8; k++)
      if (i0 + k < n) row[i0 + k + 1] = thr_excl + sacc[k];
    __syncthreads();
    if (tid == 1023) carry_s = thr_excl + run;
    __syncthreads();
  }
}

__global__ __launch_bounds__(256) void scatter2_kernel(
    const int* __restrict__ src, const int* __restrict__ dst,
    const int* __restrict__ PH, const int* __restrict__ rowU,
    const int* __restrict__ rowI, int* __restrict__ adjU,
    int* __restrict__ adjI) {
  __shared__ int pos[HSLOTS];
  const int x = blockIdx.x & (NXCD - 1);
  const int s = blockIdx.x >> 3;
  const int uLo = x * U_LOC, iLo = x * I_LOC;
  const int* pre = PH + (size_t)blockIdx.x * HSLOTS;
  for (int i = threadIdx.x; i < U_LOC; i += 256)
    pos[i] = rowU[uLo + i] + pre[i];
  for (int i = threadIdx.x; i < I_LOC; i += 256)
    pos[U_LOC + i] = rowI[iLo + i] + pre[U_LOC + i];
  __syncthreads();
  const int e0 = s * E_SLICE;
  for (int e = e0 + threadIdx.x; e < e0 + E_SLICE; e += 256) {
    const int u  = __builtin_nontemporal_load(&src[e]);
    const int it = __builtin_nontemporal_load(&dst[e]);
    const int ul = u - uLo, il = it - iLo;
    if ((unsigned)ul < (unsigned)U_LOC) {
      const int p = atomicAdd(&pos[ul], 1);
      adjU[p] = it;
    }
    if ((unsigned)il < (unsigned)I_LOC) {
      const int p = atomicAdd(&pos[U_LOC + il], 1);
      adjI[p] = u;
    }
  }
}

// ---------------- aggregations on bf16 features ----------------
__global__ __launch_bounds__(256) void agg_max_kernel(
    const unsigned short* __restrict__ feat, const int* __restrict__ rowptr,
    const int* __restrict__ adj, unsigned short* __restrict__ out, int nseg) {
  const int lane = threadIdx.x & 63;
  const int wid  = rfl((int)(threadIdx.x >> 6));
  for (int s = blockIdx.x * 4 + wid; s < nseg; s += gridDim.x * 4) {
    const int beg = rowptr[s], end = rowptr[s + 1];
    float m0 = -INFINITY, m1 = -INFINITY, m2 = -INFINITY, m3 = -INFINITY;
    int j = beg;
    for (; j + 4 <= end; j += 4) {
      const int n0 = adj[j], n1 = adj[j + 1], n2 = adj[j + 2], n3 = adj[j + 3];
      m0 = fmaxf(m0, bf2f(feat[(size_t)n0 * H + lane]));
      m1 = fmaxf(m1, bf2f(feat[(size_t)n1 * H + lane]));
      m2 = fmaxf(m2, bf2f(feat[(size_t)n2 * H + lane]));
      m3 = fmaxf(m3, bf2f(feat[(size_t)n3 * H + lane]));
    }
    for (; j < end; j++) m0 = fmaxf(m0, bf2f(feat[(size_t)adj[j] * H + lane]));
    const float m = fmaxf(fmaxf(m0, m1), fmaxf(m2, m3));
    out[(size_t)s * H + lane] = (end > beg) ? f2bf(m) : (unsigned short)0;
  }
}

__global__ __launch_bounds__(256) void agg_mean_kernel(
    const unsigned short* __restrict__ feat, const int* __restrict__ rowptr,
    const int* __restrict__ adj, unsigned short* __restrict__ out, int nseg) {
  const int lane = threadIdx.x & 63;
  const int wid  = rfl((int)(threadIdx.x >> 6));
  for (int s = blockIdx.x * 4 + wid; s < nseg; s += gridDim.x * 4) {
    const int beg = rowptr[s], end = rowptr[s + 1];
    float a0 = 0.f, a1 = 0.f, a2 = 0.f, a3 = 0.f;
    int j = beg;
    for (; j + 4 <= end; j += 4) {
      const int n0 = adj[j], n1 = adj[j + 1], n2 = adj[j + 2], n3 = adj[j + 3];
      a0 += bf2f(feat[(size_t)n0 * H + lane]);
      a1 += bf2f(feat[(size_t)n1 * H + lane]);
      a2 += bf2f(feat[(size_t)n2 * H + lane]);
      a3 += bf2f(feat[(size_t)n3 * H + lane]);
    }
    for (; j < end; j++) a0 += bf2f(feat[(size_t)adj[j] * H + lane]);
    const float inv = 1.f / (float)((end - beg) > 1 ? (end - beg) : 1);
    out[(size_t)s * H + lane] = f2bf(((a0 + a1) + (a2 + a3)) * inv);
  }
}

// ---------------- head (bf16 activations, f32 weights) ----------------
__global__ __launch_bounds__(256, 2) void head_kernel(
    const unsigned short* __restrict__ ux, const unsigned short* __restrict__ ix,
    const int* __restrict__ eliU, const int* __restrict__ eliI,
    const float* __restrict__ W1, const float* __restrict__ b1,
    const float* __restrict__ W2, const float* __restrict__ b2,
    float* __restrict__ out) {
  const int lane = threadIdx.x & 63;
  const int wid  = rfl((int)(threadIdx.x >> 6));
  float4 w1[32];
#pragma unroll
  for (int k = 0; k < 32; k++) {
    w1[k].x = W1[(k * 4 + 0) * 64 + lane];
    w1[k].y = W1[(k * 4 + 1) * 64 + lane];
    w1[k].z = W1[(k * 4 + 2) * 64 + lane];
    w1[k].w = W1[(k * 4 + 3) * 64 + lane];
  }
  const float b1v = b1[lane];
  const float w2a = W2[lane * 4 + 0], w2b = W2[lane * 4 + 1];
  const float w2c = W2[lane * 4 + 2], w2d = W2[lane * 4 + 3];
  const float cb0 = b2[0], cb1 = b2[1], cb2 = b2[2], cb3 = b2[3];
  for (int b = blockIdx.x * 4 + wid; b < NB; b += gridDim.x * 4) {
    const int u = eliU[b], it = eliI[b];
    const unsigned short* xu = ux + (size_t)u * 64;
    const unsigned short* xi = ix + (size_t)it * 64;
    float a0 = b1v, a1 = 0.f, a2 = 0.f, a3 = 0.f;
#pragma unroll
    for (int k = 0; k < 16; k++) {
      a0 = fmaf(bf2f(xu[k * 4 + 0]), w1[k].x, a0);
      a1 = fmaf(bf2f(xu[k * 4 + 1]), w1[k].y, a1);
      a2 = fmaf(bf2f(xu[k * 4 + 2]), w1[k].z, a2);
      a3 = fmaf(bf2f(xu[k * 4 + 3]), w1[k].w, a3);
    }
#pragma unroll
    for (int k = 0; k < 16; k++) {
      a0 = fmaf(bf2f(xi[k * 4 + 0]), w1[16 + k].x, a0);
      a1 = fmaf(bf2f(xi[k * 4 + 1]), w1[16 + k].y, a1);
      a2 = fmaf(bf2f(xi[k * 4 + 2]), w1[16 + k].z, a2);
      a3 = fmaf(bf2f(xi[k * 4 + 3]), w1[16 + k].w, a3);
    }
    const float h = fmaxf((a0 + a1) + (a2 + a3), 0.f);
    float o0 = h * w2a, o1 = h * w2b, o2 = h * w2c, o3 = h * w2d;
#pragma unroll
    for (int off = 32; off; off >>= 1) {
      o0 += __shfl_down(o0, off);
      o1 += __shfl_down(o1, off);
      o2 += __shfl_down(o2, off);
      o3 += __shfl_down(o3, off);
    }
    if (lane == 0) {
      float4 o = { o0 + cb0, o1 + cb1, o2 + cb2, o3 + cb3 };
      *reinterpret_cast<float4*>(out + (size_t)b * 4) = o;
    }
  }
}

// ---------------- launch ----------------
extern "C" void kernel_launch(void* const* d_in, const int* in_sizes, int n_in,
                              void* d_out, int out_size, void* d_ws, size_t ws_size,
                              hipStream_t stream) {
  const float* userF = (const float*)d_in[0];
  const float* itemF = (const float*)d_in[1];
  const int*   src   = (const int*)d_in[2];
  const int*   dst   = src + NE;
  const int*   eliU  = (const int*)d_in[3];
  const int*   eliI  = eliU + NB;
  const float* upW = (const float*)d_in[4],  *upb = (const float*)d_in[5];
  const float* ipW = (const float*)d_in[6],  *ipb = (const float*)d_in[7];
  const float* ulW = (const float*)d_in[8],  *ulb = (const float*)d_in[9];
  const float* urW = (const float*)d_in[10];
  const float* ilW = (const float*)d_in[11], *ilb = (const float*)d_in[12];
  const float* irW = (const float*)d_in[13];
  const float* ug  = (const float*)d_in[14], *ube = (const float*)d_in[15];
  const float* um  = (const float*)d_in[16], *uv  = (const float*)d_in[17];
  const float* ig  = (const float*)d_in[18], *ibe = (const float*)d_in[19];
  const float* im  = (const float*)d_in[20], *iv  = (const float*)d_in[21];
  const float* f1W = (const float*)d_in[22], *f1b = (const float*)d_in[23];
  const float* f2W = (const float*)d_in[24], *f2b = (const float*)d_in[25];
  float* outp = (float*)d_out;

  char* p = (char*)d_ws;
  auto alloc = [&](size_t bytes) {
    char* r = p;
    p += (bytes + 255) & ~(size_t)255;
    return r;
  };
  // bf16 activations
  unsigned short* ux0 = (unsigned short*)alloc((size_t)N_USERS * H * 2);  // 12.8 MB
  unsigned short* ix0 = (unsigned short*)alloc((size_t)N_ITEMS * H * 2);  //  6.4 MB
  // contiguous group aliased by PH during CSR build (all dead until agg phase):
  char* grp = alloc((size_t)38400 * 1024);  // 38.4 MB >= agU+agI+ux1+ix1
  unsigned short* agU = (unsigned short*)grp;                              // 12.8 MB
  unsigned short* agI = agU + (size_t)N_USERS * H;                         //  6.4 MB
  unsigned short* ux1 = agI + (size_t)N_ITEMS * H;                         // 12.8 MB
  unsigned short* ix1 = ux1 + (size_t)N_USERS * H;                         //  6.4 MB
  int* PH = (int*)grp;  // 512 x 18750 ints = 38.4 MB
  int*   rowU = (int*)alloc((size_t)(N_USERS + 1) * 4);
  int*   rowI = (int*)alloc((size_t)(N_ITEMS + 1) * 4);
  int*   cntU = (int*)alloc((size_t)N_USERS * 4);
  int*   cntI = (int*)alloc((size_t)N_ITEMS * 4);
  int*   adjU = (int*)alloc((size_t)NE * 4);
  int*   adjI = (int*)alloc((size_t)NE * 4);
  unsigned short* wpack = (unsigned short*)alloc((size_t)28 * 2048 * 2);  // 224 KB

  const int G = 2048, T = 256;
  pack_kernel<<<28, T, 0, stream>>>(upW, ipW, ulW, urW, ilW, irW, wpack);
  proj_mfma<256><<<(N_USERS + 63) / 64, T, 0, stream>>>(userF, wpack, upb, ux0, N_USERS);
  proj_mfma<128><<<(N_ITEMS + 63) / 64, T, 0, stream>>>(itemF, wpack + 8 * 2048, ipb, ix0, N_ITEMS);
  hist2_kernel<<<NBLK_CSR, T, 0, stream>>>(src, dst, PH);
  combine_kernel<<<(NXCD * HSLOTS + 255) / 256, T, 0, stream>>>(PH, cntU, cntI);
  scan_kernel<<<1, 1024, 0, stream>>>(cntU, rowU, N_USERS);
  scan_kernel<<<1, 1024, 0, stream>>>(cntI, rowI, N_ITEMS);
  scatter2_kernel<<<NBLK_CSR, T, 0, stream>>>(src, dst, PH, rowU, rowI, adjU, adjI);

  const unsigned short* uin = ux0;
  const unsigned short* iin = ix0;
  unsigned short* uout = ux1;
  unsigned short* iout = ix1;
  const int GU = (N_USERS + 63) / 64, GI = (N_ITEMS + 63) / 64;
  for (int l = 0; l < 2; l++) {
    unsigned short* cwU = wpack + (12 + 4 * (0 + l)) * 2048;  // t = l     (user)
    unsigned short* cwI = wpack + (12 + 4 * (2 + l)) * 2048;  // t = 2 + l (item)
    agg_max_kernel<<<G, T, 0, stream>>>(iin, rowU, adjU, agU, N_USERS);
    conv_mfma<<<GU, T, 0, stream>>>(agU, uin, cwU, ulb + l * 64,
                                    ug + l * 64, ube + l * 64,
                                    um + l * 64, uv + l * 64, uout, N_USERS);
    agg_mean_kernel<<<G, T, 0, stream>>>(uin, rowI, adjI, agI, N_ITEMS);
    conv_mfma<<<GI, T, 0, stream>>>(agI, iin, cwI, ilb + l * 64,
                                    ig + l * 64, ibe + l * 64,
                                    im + l * 64, iv + l * 64, iout, N_ITEMS);
    const unsigned short* t;
    t = uin; uin = uout; uout = (unsigned short*)t;
    t = iin; iin = iout; iout = (unsigned short*)t;
  }
  head_kernel<<<G, T, 0, stream>>>(uin, iin, eliU, eliI, f1W, f1b, f2W, f2b, outp);
}

// Round 8
// 588.229 us; speedup vs baseline: 1.7038x; 1.2053x over previous
//
#include <hip/hip_runtime.h>
#include <math.h>

#define N_USERS 100000
#define N_ITEMS 50000
#define NE      2000000
#define NB      100000
#define H       64
#define BN_EPS  1e-5f
#define P_PART  16                         // node partitions (2 per XCD)
#define U_LOC   (N_USERS / P_PART)         // 6250
#define I_LOC   (N_ITEMS / P_PART)         // 3125
#define HSLOTS  (U_LOC + I_LOC)            // 9375 ints = 37.5 KB LDS
#define S_SLICES 50
#define NBLK_CSR (P_PART * S_SLICES)       // 800
#define E_SLICE  (NE / S_SLICES)           // 40000 (mult of 4, 16B-aligned)
#define Q_SLICE  (E_SLICE / 4)             // 10000 int4 quads

typedef __attribute__((ext_vector_type(8))) short bf16x8;
typedef __attribute__((ext_vector_type(4))) float f32x4;

static __device__ __forceinline__ int rfl(int x) { return __builtin_amdgcn_readfirstlane(x); }

static __device__ __forceinline__ unsigned short f2bf(float f) {   // RTNE
  union { float f; unsigned u; } v; v.f = f;
  const unsigned r = v.u + 0x7fffu + ((v.u >> 16) & 1u);
  return (unsigned short)(r >> 16);
}
static __device__ __forceinline__ float bf2f(unsigned short h) {
  union { unsigned u; float f; } v; v.u = (unsigned)h << 16;
  return v.f;
}

// ---------------- weight pre-pack into MFMA fragment order ----------------
__global__ __launch_bounds__(256) void pack_kernel(
    const float* __restrict__ upW, const float* __restrict__ ipW,
    const float* __restrict__ ulW, const float* __restrict__ urW,
    const float* __restrict__ ilW, const float* __restrict__ irW,
    unsigned short* __restrict__ dst) {
  const int b = blockIdx.x;
  const int ct = threadIdx.x >> 6, lane = threadIdx.x & 63;
  const float* src;
  int krow0;
  if (b < 8)       { src = upW; krow0 = b * 32; }
  else if (b < 12) { src = ipW; krow0 = (b - 8) * 32; }
  else {
    const int idx = b - 12, t = idx >> 2, ks = idx & 3;
    const int layer = t & 1;
    const float* Wl = (t < 2) ? ulW : ilW;
    const float* Wr = (t < 2) ? urW : irW;
    src = ((ks < 2) ? Wl : Wr) + layer * 4096;
    krow0 = ((ks < 2) ? ks : ks - 2) * 32;
  }
  unsigned short* out = dst + (size_t)b * 2048 + ((size_t)ct * 64 + lane) * 8;
  const int col = ct * 16 + (lane & 15);
  const int kr = krow0 + (lane >> 4) * 8;
#pragma unroll
  for (int j = 0; j < 8; j++) out[j] = f2bf(src[(kr + j) * 64 + col]);
}

// ---------------- proj: Y[N,64] = bf16(X[N,K] @ W + b) via MFMA ----------------
template<int K>
__global__ __launch_bounds__(256) void proj_mfma(
    const float* __restrict__ X, const unsigned short* __restrict__ Wf,
    const float* __restrict__ bias, unsigned short* __restrict__ Y, int nrows) {
  const int lane = threadIdx.x & 63;
  const int wave = rfl((int)(threadIdx.x >> 6));
  const int r0 = (blockIdx.x * 4 + wave) * 16;
  if (r0 >= nrows) return;
  const int arow = r0 + (lane & 15);
  const int ar = arow < nrows ? arow : nrows - 1;
  const int k0 = (lane >> 4) * 8;
  f32x4 acc[4] = {};
#pragma unroll
  for (int ks = 0; ks < K / 32; ks++) {
    const float* xp = X + (size_t)ar * K + ks * 32 + k0;
    const float4 xa = *reinterpret_cast<const float4*>(xp);
    const float4 xb = *reinterpret_cast<const float4*>(xp + 4);
    bf16x8 af;
    af[0] = f2bf(xa.x); af[1] = f2bf(xa.y); af[2] = f2bf(xa.z); af[3] = f2bf(xa.w);
    af[4] = f2bf(xb.x); af[5] = f2bf(xb.y); af[6] = f2bf(xb.z); af[7] = f2bf(xb.w);
#pragma unroll
    for (int ct = 0; ct < 4; ct++) {
      const bf16x8 bfr = *reinterpret_cast<const bf16x8*>(
          Wf + ((size_t)(ks * 4 + ct) * 64 + lane) * 8);
      acc[ct] = __builtin_amdgcn_mfma_f32_16x16x32_bf16(af, bfr, acc[ct], 0, 0, 0);
    }
  }
  const int orow0 = r0 + (lane >> 4) * 4;
#pragma unroll
  for (int ct = 0; ct < 4; ct++) {
    const int col = ct * 16 + (lane & 15);
    const float bv = bias[col];
#pragma unroll
    for (int i = 0; i < 4; i++) {
      const int r = orow0 + i;
      if (r < nrows) Y[(size_t)r * 64 + col] = f2bf(acc[ct][i] + bv);
    }
  }
}

// ---------------- conv: Y = bf16(relu(BN([AGG|XS] @ [Wl;Wr] + bl))) ----------------
__global__ __launch_bounds__(256) void conv_mfma(
    const unsigned short* __restrict__ AGG, const unsigned short* __restrict__ XS,
    const unsigned short* __restrict__ Wf, const float* __restrict__ bl,
    const float* __restrict__ gm, const float* __restrict__ bt,
    const float* __restrict__ mu, const float* __restrict__ vr,
    unsigned short* __restrict__ Y, int nrows) {
  const int lane = threadIdx.x & 63;
  const int wave = rfl((int)(threadIdx.x >> 6));
  const int r0 = (blockIdx.x * 4 + wave) * 16;
  if (r0 >= nrows) return;
  const int arow = r0 + (lane & 15);
  const int ar = arow < nrows ? arow : nrows - 1;
  const int k0 = (lane >> 4) * 8;
  f32x4 acc[4] = {};
#pragma unroll
  for (int ks = 0; ks < 4; ks++) {
    const unsigned short* ap =
        (ks < 2 ? AGG : XS) + (size_t)ar * 64 + (ks & 1) * 32 + k0;
    const bf16x8 af = *reinterpret_cast<const bf16x8*>(ap);
#pragma unroll
    for (int ct = 0; ct < 4; ct++) {
      const bf16x8 bfr = *reinterpret_cast<const bf16x8*>(
          Wf + ((size_t)(ks * 4 + ct) * 64 + lane) * 8);
      acc[ct] = __builtin_amdgcn_mfma_f32_16x16x32_bf16(af, bfr, acc[ct], 0, 0, 0);
    }
  }
  const int orow0 = r0 + (lane >> 4) * 4;
#pragma unroll
  for (int ct = 0; ct < 4; ct++) {
    const int col = ct * 16 + (lane & 15);
    const float s = gm[col] * rsqrtf(vr[col] + BN_EPS);
    const float C = (bl[col] - mu[col]) * s + bt[col];
#pragma unroll
    for (int i = 0; i < 4; i++) {
      const int r = orow0 + i;
      if (r < nrows)
        Y[(size_t)r * 64 + col] = f2bf(fmaxf(fmaf(acc[ct][i], s, C), 0.f));
    }
  }
}

// ---------------- CSR build: P=16 partitions, int4 edge loads ----------------
// block b: partition p = b&15 (-> XCD p%8), slice s = b>>4.
__global__ __launch_bounds__(256) void hist2_kernel(
    const int* __restrict__ src, const int* __restrict__ dst,
    int* __restrict__ PH) {
  __shared__ int h[HSLOTS];
  const int p = blockIdx.x & (P_PART - 1);
  const int s = blockIdx.x >> 4;
  for (int i = threadIdx.x; i < HSLOTS; i += 256) h[i] = 0;
  __syncthreads();
  const int uLo = p * U_LOC, iLo = p * I_LOC;
  const int e0 = s * E_SLICE;
  const int4* s4 = reinterpret_cast<const int4*>(src + e0);
  const int4* d4 = reinterpret_cast<const int4*>(dst + e0);
  for (int i = threadIdx.x; i < Q_SLICE; i += 256) {
    const int4 us = s4[i];
    const int4 ds = d4[i];
    int ul, il;
    ul = us.x - uLo; if ((unsigned)ul < (unsigned)U_LOC) atomicAdd(&h[ul], 1);
    ul = us.y - uLo; if ((unsigned)ul < (unsigned)U_LOC) atomicAdd(&h[ul], 1);
    ul = us.z - uLo; if ((unsigned)ul < (unsigned)U_LOC) atomicAdd(&h[ul], 1);
    ul = us.w - uLo; if ((unsigned)ul < (unsigned)U_LOC) atomicAdd(&h[ul], 1);
    il = ds.x - iLo; if ((unsigned)il < (unsigned)I_LOC) atomicAdd(&h[U_LOC + il], 1);
    il = ds.y - iLo; if ((unsigned)il < (unsigned)I_LOC) atomicAdd(&h[U_LOC + il], 1);
    il = ds.z - iLo; if ((unsigned)il < (unsigned)I_LOC) atomicAdd(&h[U_LOC + il], 1);
    il = ds.w - iLo; if ((unsigned)il < (unsigned)I_LOC) atomicAdd(&h[U_LOC + il], 1);
  }
  __syncthreads();
  int* out = PH + (size_t)blockIdx.x * HSLOTS;
  for (int i = threadIdx.x; i < HSLOTS; i += 256) out[i] = h[i];
}

__global__ __launch_bounds__(256) void combine_kernel(
    int* __restrict__ PH, int* __restrict__ cntU, int* __restrict__ cntI) {
  const int g = blockIdx.x * 256 + threadIdx.x;
  if (g >= P_PART * HSLOTS) return;
  const int x = g / HSLOTS;
  const int n = g - x * HSLOTS;
  int* p = PH + (size_t)x * HSLOTS + n;
  int run = 0;
#pragma unroll 2
  for (int s = 0; s < S_SLICES; s++) {
    int* q = p + (size_t)s * (P_PART * HSLOTS);
    const int v = *q;
    *q = run;
    run += v;
  }
  if (n < U_LOC) cntU[x * U_LOC + n] = run;
  else           cntI[x * I_LOC + (n - U_LOC)] = run;
}

__global__ __launch_bounds__(1024) void scan_kernel(
    const int* __restrict__ cnt, int* __restrict__ row, int n) {
  __shared__ int wtot[16];
  __shared__ int carry_s;
  const int tid = threadIdx.x;
  const int lane = tid & 63, wv = tid >> 6;
  if (tid == 0) { carry_s = 0; row[0] = 0; }
  __syncthreads();
  for (int base = 0; base < n; base += 8192) {
    const int i0 = base + tid * 8;
    int v, sacc[8];
    int run = 0;
#pragma unroll
    for (int k = 0; k < 8; k++) {
      v = (i0 + k < n) ? cnt[i0 + k] : 0;
      run += v;
      sacc[k] = run;
    }
    int x = run;
#pragma unroll
    for (int off = 1; off < 64; off <<= 1) {
      const int y = __shfl_up(x, off);
      if (lane >= off) x += y;
    }
    if (lane == 63) wtot[wv] = x;
    __syncthreads();
    int woff = 0;
#pragma unroll
    for (int k = 0; k < 16; k++) woff += (k < wv) ? wtot[k] : 0;
    const int thr_excl = (x - run) + woff + carry_s;
#pragma unroll
    for (int k = 0; k < 8; k++)
      if (i0 + k < n) row[i0 + k + 1] = thr_excl + sacc[k];
    __syncthreads();
    if (tid == 1023) carry_s = thr_excl + run;
    __syncthreads();
  }
}

__global__ __launch_bounds__(256) void scatter2_kernel(
    const int* __restrict__ src, const int* __restrict__ dst,
    const int* __restrict__ PH, const int* __restrict__ rowU,
    const int* __restrict__ rowI, int* __restrict__ adjU,
    int* __restrict__ adjI) {
  __shared__ int pos[HSLOTS];
  const int p = blockIdx.x & (P_PART - 1);
  const int s = blockIdx.x >> 4;
  const int uLo = p * U_LOC, iLo = p * I_LOC;
  const int* pre = PH + (size_t)blockIdx.x * HSLOTS;
  for (int i = threadIdx.x; i < U_LOC; i += 256)
    pos[i] = rowU[uLo + i] + pre[i];
  for (int i = threadIdx.x; i < I_LOC; i += 256)
    pos[U_LOC + i] = rowI[iLo + i] + pre[U_LOC + i];
  __syncthreads();
  const int e0 = s * E_SLICE;
  const int4* s4 = reinterpret_cast<const int4*>(src + e0);
  const int4* d4 = reinterpret_cast<const int4*>(dst + e0);
  for (int i = threadIdx.x; i < Q_SLICE; i += 256) {
    const int4 us = s4[i];
    const int4 ds = d4[i];
#pragma unroll
    for (int q = 0; q < 4; q++) {
      const int u  = (q == 0) ? us.x : (q == 1) ? us.y : (q == 2) ? us.z : us.w;
      const int it = (q == 0) ? ds.x : (q == 1) ? ds.y : (q == 2) ? ds.z : ds.w;
      const int ul = u - uLo, il = it - iLo;
      if ((unsigned)ul < (unsigned)U_LOC) {
        const int pp = atomicAdd(&pos[ul], 1);
        adjU[pp] = it;
      }
      if ((unsigned)il < (unsigned)I_LOC) {
        const int pp = atomicAdd(&pos[U_LOC + il], 1);
        adjI[pp] = u;
      }
    }
  }
}

// ---------------- aggregations on bf16 features (8-deep unroll) ----------------
__global__ __launch_bounds__(256) void agg_max_kernel(
    const unsigned short* __restrict__ feat, const int* __restrict__ rowptr,
    const int* __restrict__ adj, unsigned short* __restrict__ out, int nseg) {
  const int lane = threadIdx.x & 63;
  const int wid  = rfl((int)(threadIdx.x >> 6));
  for (int s = blockIdx.x * 4 + wid; s < nseg; s += gridDim.x * 4) {
    const int beg = rowptr[s], end = rowptr[s + 1];
    float m0 = -INFINITY, m1 = -INFINITY, m2 = -INFINITY, m3 = -INFINITY;
    float m4 = -INFINITY, m5 = -INFINITY, m6 = -INFINITY, m7 = -INFINITY;
    int j = beg;
    for (; j + 8 <= end; j += 8) {
      m0 = fmaxf(m0, bf2f(feat[(size_t)adj[j + 0] * H + lane]));
      m1 = fmaxf(m1, bf2f(feat[(size_t)adj[j + 1] * H + lane]));
      m2 = fmaxf(m2, bf2f(feat[(size_t)adj[j + 2] * H + lane]));
      m3 = fmaxf(m3, bf2f(feat[(size_t)adj[j + 3] * H + lane]));
      m4 = fmaxf(m4, bf2f(feat[(size_t)adj[j + 4] * H + lane]));
      m5 = fmaxf(m5, bf2f(feat[(size_t)adj[j + 5] * H + lane]));
      m6 = fmaxf(m6, bf2f(feat[(size_t)adj[j + 6] * H + lane]));
      m7 = fmaxf(m7, bf2f(feat[(size_t)adj[j + 7] * H + lane]));
    }
    for (; j < end; j++) m0 = fmaxf(m0, bf2f(feat[(size_t)adj[j] * H + lane]));
    const float m = fmaxf(fmaxf(fmaxf(m0, m1), fmaxf(m2, m3)),
                          fmaxf(fmaxf(m4, m5), fmaxf(m6, m7)));
    out[(size_t)s * H + lane] = (end > beg) ? f2bf(m) : (unsigned short)0;
  }
}

__global__ __launch_bounds__(256) void agg_mean_kernel(
    const unsigned short* __restrict__ feat, const int* __restrict__ rowptr,
    const int* __restrict__ adj, unsigned short* __restrict__ out, int nseg) {
  const int lane = threadIdx.x & 63;
  const int wid  = rfl((int)(threadIdx.x >> 6));
  for (int s = blockIdx.x * 4 + wid; s < nseg; s += gridDim.x * 4) {
    const int beg = rowptr[s], end = rowptr[s + 1];
    float a0 = 0.f, a1 = 0.f, a2 = 0.f, a3 = 0.f;
    float a4 = 0.f, a5 = 0.f, a6 = 0.f, a7 = 0.f;
    int j = beg;
    for (; j + 8 <= end; j += 8) {
      a0 += bf2f(feat[(size_t)adj[j + 0] * H + lane]);
      a1 += bf2f(feat[(size_t)adj[j + 1] * H + lane]);
      a2 += bf2f(feat[(size_t)adj[j + 2] * H + lane]);
      a3 += bf2f(feat[(size_t)adj[j + 3] * H + lane]);
      a4 += bf2f(feat[(size_t)adj[j + 4] * H + lane]);
      a5 += bf2f(feat[(size_t)adj[j + 5] * H + lane]);
      a6 += bf2f(feat[(size_t)adj[j + 6] * H + lane]);
      a7 += bf2f(feat[(size_t)adj[j + 7] * H + lane]);
    }
    for (; j < end; j++) a0 += bf2f(feat[(size_t)adj[j] * H + lane]);
    const float inv = 1.f / (float)((end - beg) > 1 ? (end - beg) : 1);
    out[(size_t)s * H + lane] =
        f2bf((((a0 + a1) + (a2 + a3)) + ((a4 + a5) + (a6 + a7))) * inv);
  }
}

// ---------------- head (bf16 activations, f32 weights) ----------------
__global__ __launch_bounds__(256, 2) void head_kernel(
    const unsigned short* __restrict__ ux, const unsigned short* __restrict__ ix,
    const int* __restrict__ eliU, const int* __restrict__ eliI,
    const float* __restrict__ W1, const float* __restrict__ b1,
    const float* __restrict__ W2, const float* __restrict__ b2,
    float* __restrict__ out) {
  const int lane = threadIdx.x & 63;
  const int wid  = rfl((int)(threadIdx.x >> 6));
  float4 w1[32];
#pragma unroll
  for (int k = 0; k < 32; k++) {
    w1[k].x = W1[(k * 4 + 0) * 64 + lane];
    w1[k].y = W1[(k * 4 + 1) * 64 + lane];
    w1[k].z = W1[(k * 4 + 2) * 64 + lane];
    w1[k].w = W1[(k * 4 + 3) * 64 + lane];
  }
  const float b1v = b1[lane];
  const float w2a = W2[lane * 4 + 0], w2b = W2[lane * 4 + 1];
  const float w2c = W2[lane * 4 + 2], w2d = W2[lane * 4 + 3];
  const float cb0 = b2[0], cb1 = b2[1], cb2 = b2[2], cb3 = b2[3];
  for (int b = blockIdx.x * 4 + wid; b < NB; b += gridDim.x * 4) {
    const int u = eliU[b], it = eliI[b];
    const unsigned short* xu = ux + (size_t)u * 64;
    const unsigned short* xi = ix + (size_t)it * 64;
    float a0 = b1v, a1 = 0.f, a2 = 0.f, a3 = 0.f;
#pragma unroll
    for (int k = 0; k < 16; k++) {
      a0 = fmaf(bf2f(xu[k * 4 + 0]), w1[k].x, a0);
      a1 = fmaf(bf2f(xu[k * 4 + 1]), w1[k].y, a1);
      a2 = fmaf(bf2f(xu[k * 4 + 2]), w1[k].z, a2);
      a3 = fmaf(bf2f(xu[k * 4 + 3]), w1[k].w, a3);
    }
#pragma unroll
    for (int k = 0; k < 16; k++) {
      a0 = fmaf(bf2f(xi[k * 4 + 0]), w1[16 + k].x, a0);
      a1 = fmaf(bf2f(xi[k * 4 + 1]), w1[16 + k].y, a1);
      a2 = fmaf(bf2f(xi[k * 4 + 2]), w1[16 + k].z, a2);
      a3 = fmaf(bf2f(xi[k * 4 + 3]), w1[16 + k].w, a3);
    }
    const float h = fmaxf((a0 + a1) + (a2 + a3), 0.f);
    float o0 = h * w2a, o1 = h * w2b, o2 = h * w2c, o3 = h * w2d;
#pragma unroll
    for (int off = 32; off; off >>= 1) {
      o0 += __shfl_down(o0, off);
      o1 += __shfl_down(o1, off);
      o2 += __shfl_down(o2, off);
      o3 += __shfl_down(o3, off);
    }
    if (lane == 0) {
      float4 o = { o0 + cb0, o1 + cb1, o2 + cb2, o3 + cb3 };
      *reinterpret_cast<float4*>(out + (size_t)b * 4) = o;
    }
  }
}

// ---------------- launch ----------------
extern "C" void kernel_launch(void* const* d_in, const int* in_sizes, int n_in,
                              void* d_out, int out_size, void* d_ws, size_t ws_size,
                              hipStream_t stream) {
  const float* userF = (const float*)d_in[0];
  const float* itemF = (const float*)d_in[1];
  const int*   src   = (const int*)d_in[2];
  const int*   dst   = src + NE;
  const int*   eliU  = (const int*)d_in[3];
  const int*   eliI  = eliU + NB;
  const float* upW = (const float*)d_in[4],  *upb = (const float*)d_in[5];
  const float* ipW = (const float*)d_in[6],  *ipb = (const float*)d_in[7];
  const float* ulW = (const float*)d_in[8],  *ulb = (const float*)d_in[9];
  const float* urW = (const float*)d_in[10];
  const float* ilW = (const float*)d_in[11], *ilb = (const float*)d_in[12];
  const float* irW = (const float*)d_in[13];
  const float* ug  = (const float*)d_in[14], *ube = (const float*)d_in[15];
  const float* um  = (const float*)d_in[16], *uv  = (const float*)d_in[17];
  const float* ig  = (const float*)d_in[18], *ibe = (const float*)d_in[19];
  const float* im  = (const float*)d_in[20], *iv  = (const float*)d_in[21];
  const float* f1W = (const float*)d_in[22], *f1b = (const float*)d_in[23];
  const float* f2W = (const float*)d_in[24], *f2b = (const float*)d_in[25];
  float* outp = (float*)d_out;

  char* p = (char*)d_ws;
  auto alloc = [&](size_t bytes) {
    char* r = p;
    p += (bytes + 255) & ~(size_t)255;
    return r;
  };
  unsigned short* ux0 = (unsigned short*)alloc((size_t)N_USERS * H * 2);  // 12.8 MB
  unsigned short* ix0 = (unsigned short*)alloc((size_t)N_ITEMS * H * 2);  //  6.4 MB
  // group aliased by PH during CSR build (dead until agg phase):
  char* grp = alloc((size_t)38400 * 1024);  // 38.4 MB >= max(PH 30MB, agU+agI+ux1+ix1)
  unsigned short* agU = (unsigned short*)grp;
  unsigned short* agI = agU + (size_t)N_USERS * H;
  unsigned short* ux1 = agI + (size_t)N_ITEMS * H;
  unsigned short* ix1 = ux1 + (size_t)N_USERS * H;
  int* PH = (int*)grp;  // 800 x 9375 ints = 30 MB
  int*   rowU = (int*)alloc((size_t)(N_USERS + 1) * 4);
  int*   rowI = (int*)alloc((size_t)(N_ITEMS + 1) * 4);
  int*   cntU = (int*)alloc((size_t)N_USERS * 4);
  int*   cntI = (int*)alloc((size_t)N_ITEMS * 4);
  int*   adjU = (int*)alloc((size_t)NE * 4);
  int*   adjI = (int*)alloc((size_t)NE * 4);
  unsigned short* wpack = (unsigned short*)alloc((size_t)28 * 2048 * 2);  // 224 KB

  const int G = 2048, T = 256;
  pack_kernel<<<28, T, 0, stream>>>(upW, ipW, ulW, urW, ilW, irW, wpack);
  proj_mfma<256><<<(N_USERS + 63) / 64, T, 0, stream>>>(userF, wpack, upb, ux0, N_USERS);
  proj_mfma<128><<<(N_ITEMS + 63) / 64, T, 0, stream>>>(itemF, wpack + 8 * 2048, ipb, ix0, N_ITEMS);
  hist2_kernel<<<NBLK_CSR, T, 0, stream>>>(src, dst, PH);
  combine_kernel<<<(P_PART * HSLOTS + 255) / 256, T, 0, stream>>>(PH, cntU, cntI);
  scan_kernel<<<1, 1024, 0, stream>>>(cntU, rowU, N_USERS);
  scan_kernel<<<1, 1024, 0, stream>>>(cntI, rowI, N_ITEMS);
  scatter2_kernel<<<NBLK_CSR, T, 0, stream>>>(src, dst, PH, rowU, rowI, adjU, adjI);

  const unsigned short* uin = ux0;
  const unsigned short* iin = ix0;
  unsigned short* uout = ux1;
  unsigned short* iout = ix1;
  const int GU = (N_USERS + 63) / 64, GI = (N_ITEMS + 63) / 64;
  for (int l = 0; l < 2; l++) {
    unsigned short* cwU = wpack + (12 + 4 * (0 + l)) * 2048;
    unsigned short* cwI = wpack + (12 + 4 * (2 + l)) * 2048;
    agg_max_kernel<<<G, T, 0, stream>>>(iin, rowU, adjU, agU, N_USERS);
    conv_mfma<<<GU, T, 0, stream>>>(agU, uin, cwU, ulb + l * 64,
                                    ug + l * 64, ube + l * 64,
                                    um + l * 64, uv + l * 64, uout, N_USERS);
    agg_mean_kernel<<<G, T, 0, stream>>>(uin, rowI, adjI, agI, N_ITEMS);
    conv_mfma<<<GI, T, 0, stream>>>(agI, iin, cwI, ilb + l * 64,
                                    ig + l * 64, ibe + l * 64,
                                    im + l * 64, iv + l * 64, iout, N_ITEMS);
    const unsigned short* t;
    t = uin; uin = uout; uout = (unsigned short*)t;
    t = iin; iin = iout; iout = (unsigned short*)t;
  }
  head_kernel<<<G, T, 0, stream>>>(uin, iin, eliU, eliI, f1W, f1b, f2W, f2b, outp);
}

// Round 9
// 506.175 us; speedup vs baseline: 1.9800x; 1.1621x over previous
//
#include <hip/hip_runtime.h>
#include <math.h>

#define N_USERS 100000
#define N_ITEMS 50000
#define NE      2000000
#define NB      100000
#define H       64
#define BN_EPS  1e-5f
#define P_PART  16                         // node partitions (2 per XCD)
#define U_LOC   (N_USERS / P_PART)         // 6250
#define I_LOC   (N_ITEMS / P_PART)         // 3125
#define HSLOTS  (U_LOC + I_LOC)            // 9375 ints = 37.5 KB LDS
#define S_SLICES 50
#define NBLK_CSR (P_PART * S_SLICES)       // 800
#define E_SLICE  (NE / S_SLICES)           // 40000 (mult of 4, 16B-aligned)
#define Q_SLICE  (E_SLICE / 4)             // 10000 int4 quads

typedef __attribute__((ext_vector_type(8))) short bf16x8;
typedef __attribute__((ext_vector_type(4))) float f32x4;

static __device__ __forceinline__ int rfl(int x) { return __builtin_amdgcn_readfirstlane(x); }

static __device__ __forceinline__ unsigned short f2bf(float f) {   // RTNE
  union { float f; unsigned u; } v; v.f = f;
  const unsigned r = v.u + 0x7fffu + ((v.u >> 16) & 1u);
  return (unsigned short)(r >> 16);
}
static __device__ __forceinline__ float bf2f(unsigned short h) {
  union { unsigned u; float f; } v; v.u = (unsigned)h << 16;
  return v.f;
}

// ---------------- weight pre-pack into MFMA fragment order ----------------
// blocks 0..7: user proj (K=256); 8..11: item proj (K=128);
// 12..27: conv tables; 28..31: fc1 head (K=128).
__global__ __launch_bounds__(256) void pack_kernel(
    const float* __restrict__ upW, const float* __restrict__ ipW,
    const float* __restrict__ ulW, const float* __restrict__ urW,
    const float* __restrict__ ilW, const float* __restrict__ irW,
    const float* __restrict__ f1W, unsigned short* __restrict__ dst) {
  const int b = blockIdx.x;
  const int ct = threadIdx.x >> 6, lane = threadIdx.x & 63;
  const float* src;
  int krow0;
  if (b < 8)       { src = upW; krow0 = b * 32; }
  else if (b < 12) { src = ipW; krow0 = (b - 8) * 32; }
  else if (b < 28) {
    const int idx = b - 12, t = idx >> 2, ks = idx & 3;
    const int layer = t & 1;
    const float* Wl = (t < 2) ? ulW : ilW;
    const float* Wr = (t < 2) ? urW : irW;
    src = ((ks < 2) ? Wl : Wr) + layer * 4096;
    krow0 = ((ks < 2) ? ks : ks - 2) * 32;
  } else { src = f1W; krow0 = (b - 28) * 32; }
  unsigned short* out = dst + (size_t)b * 2048 + ((size_t)ct * 64 + lane) * 8;
  const int col = ct * 16 + (lane & 15);
  const int kr = krow0 + (lane >> 4) * 8;
#pragma unroll
  for (int j = 0; j < 8; j++) out[j] = f2bf(src[(kr + j) * 64 + col]);
}

// ---------------- proj: Y[N,64] = bf16(X[N,K] @ W + b) via MFMA ----------------
template<int K>
__global__ __launch_bounds__(256) void proj_mfma(
    const float* __restrict__ X, const unsigned short* __restrict__ Wf,
    const float* __restrict__ bias, unsigned short* __restrict__ Y, int nrows) {
  const int lane = threadIdx.x & 63;
  const int wave = rfl((int)(threadIdx.x >> 6));
  const int r0 = (blockIdx.x * 4 + wave) * 16;
  if (r0 >= nrows) return;
  const int arow = r0 + (lane & 15);
  const int ar = arow < nrows ? arow : nrows - 1;
  const int k0 = (lane >> 4) * 8;
  f32x4 acc[4] = {};
#pragma unroll
  for (int ks = 0; ks < K / 32; ks++) {
    const float* xp = X + (size_t)ar * K + ks * 32 + k0;
    const float4 xa = *reinterpret_cast<const float4*>(xp);
    const float4 xb = *reinterpret_cast<const float4*>(xp + 4);
    bf16x8 af;
    af[0] = f2bf(xa.x); af[1] = f2bf(xa.y); af[2] = f2bf(xa.z); af[3] = f2bf(xa.w);
    af[4] = f2bf(xb.x); af[5] = f2bf(xb.y); af[6] = f2bf(xb.z); af[7] = f2bf(xb.w);
#pragma unroll
    for (int ct = 0; ct < 4; ct++) {
      const bf16x8 bfr = *reinterpret_cast<const bf16x8*>(
          Wf + ((size_t)(ks * 4 + ct) * 64 + lane) * 8);
      acc[ct] = __builtin_amdgcn_mfma_f32_16x16x32_bf16(af, bfr, acc[ct], 0, 0, 0);
    }
  }
  const int orow0 = r0 + (lane >> 4) * 4;
#pragma unroll
  for (int ct = 0; ct < 4; ct++) {
    const int col = ct * 16 + (lane & 15);
    const float bv = bias[col];
#pragma unroll
    for (int i = 0; i < 4; i++) {
      const int r = orow0 + i;
      if (r < nrows) Y[(size_t)r * 64 + col] = f2bf(acc[ct][i] + bv);
    }
  }
}

// ---------------- conv: Y = bf16(relu(BN([AGG|XS] @ [Wl;Wr] + bl))) ----------------
__global__ __launch_bounds__(256) void conv_mfma(
    const unsigned short* __restrict__ AGG, const unsigned short* __restrict__ XS,
    const unsigned short* __restrict__ Wf, const float* __restrict__ bl,
    const float* __restrict__ gm, const float* __restrict__ bt,
    const float* __restrict__ mu, const float* __restrict__ vr,
    unsigned short* __restrict__ Y, int nrows) {
  const int lane = threadIdx.x & 63;
  const int wave = rfl((int)(threadIdx.x >> 6));
  const int r0 = (blockIdx.x * 4 + wave) * 16;
  if (r0 >= nrows) return;
  const int arow = r0 + (lane & 15);
  const int ar = arow < nrows ? arow : nrows - 1;
  const int k0 = (lane >> 4) * 8;
  f32x4 acc[4] = {};
#pragma unroll
  for (int ks = 0; ks < 4; ks++) {
    const unsigned short* ap =
        (ks < 2 ? AGG : XS) + (size_t)ar * 64 + (ks & 1) * 32 + k0;
    const bf16x8 af = *reinterpret_cast<const bf16x8*>(ap);
#pragma unroll
    for (int ct = 0; ct < 4; ct++) {
      const bf16x8 bfr = *reinterpret_cast<const bf16x8*>(
          Wf + ((size_t)(ks * 4 + ct) * 64 + lane) * 8);
      acc[ct] = __builtin_amdgcn_mfma_f32_16x16x32_bf16(af, bfr, acc[ct], 0, 0, 0);
    }
  }
  const int orow0 = r0 + (lane >> 4) * 4;
#pragma unroll
  for (int ct = 0; ct < 4; ct++) {
    const int col = ct * 16 + (lane & 15);
    const float s = gm[col] * rsqrtf(vr[col] + BN_EPS);
    const float C = (bl[col] - mu[col]) * s + bt[col];
#pragma unroll
    for (int i = 0; i < 4; i++) {
      const int r = orow0 + i;
      if (r < nrows)
        Y[(size_t)r * 64 + col] = f2bf(fmaxf(fmaf(acc[ct][i], s, C), 0.f));
    }
  }
}

// ---------------- CSR build: P=16 partitions, int4 edge loads ----------------
__global__ __launch_bounds__(256) void hist2_kernel(
    const int* __restrict__ src, const int* __restrict__ dst,
    int* __restrict__ PH) {
  __shared__ int h[HSLOTS];
  const int p = blockIdx.x & (P_PART - 1);
  const int s = blockIdx.x >> 4;
  for (int i = threadIdx.x; i < HSLOTS; i += 256) h[i] = 0;
  __syncthreads();
  const int uLo = p * U_LOC, iLo = p * I_LOC;
  const int e0 = s * E_SLICE;
  const int4* s4 = reinterpret_cast<const int4*>(src + e0);
  const int4* d4 = reinterpret_cast<const int4*>(dst + e0);
  for (int i = threadIdx.x; i < Q_SLICE; i += 256) {
    const int4 us = s4[i];
    const int4 ds = d4[i];
    int ul, il;
    ul = us.x - uLo; if ((unsigned)ul < (unsigned)U_LOC) atomicAdd(&h[ul], 1);
    ul = us.y - uLo; if ((unsigned)ul < (unsigned)U_LOC) atomicAdd(&h[ul], 1);
    ul = us.z - uLo; if ((unsigned)ul < (unsigned)U_LOC) atomicAdd(&h[ul], 1);
    ul = us.w - uLo; if ((unsigned)ul < (unsigned)U_LOC) atomicAdd(&h[ul], 1);
    il = ds.x - iLo; if ((unsigned)il < (unsigned)I_LOC) atomicAdd(&h[U_LOC + il], 1);
    il = ds.y - iLo; if ((unsigned)il < (unsigned)I_LOC) atomicAdd(&h[U_LOC + il], 1);
    il = ds.z - iLo; if ((unsigned)il < (unsigned)I_LOC) atomicAdd(&h[U_LOC + il], 1);
    il = ds.w - iLo; if ((unsigned)il < (unsigned)I_LOC) atomicAdd(&h[U_LOC + il], 1);
  }
  __syncthreads();
  int* out = PH + (size_t)blockIdx.x * HSLOTS;
  for (int i = threadIdx.x; i < HSLOTS; i += 256) out[i] = h[i];
}

__global__ __launch_bounds__(256) void combine_kernel(
    int* __restrict__ PH, int* __restrict__ cntU, int* __restrict__ cntI) {
  const int g = blockIdx.x * 256 + threadIdx.x;
  if (g >= P_PART * HSLOTS) return;
  const int x = g / HSLOTS;
  const int n = g - x * HSLOTS;
  int* p = PH + (size_t)x * HSLOTS + n;
  int run = 0;
#pragma unroll 2
  for (int s = 0; s < S_SLICES; s++) {
    int* q = p + (size_t)s * (P_PART * HSLOTS);
    const int v = *q;
    *q = run;
    run += v;
  }
  if (n < U_LOC) cntU[x * U_LOC + n] = run;
  else           cntI[x * I_LOC + (n - U_LOC)] = run;
}

__global__ __launch_bounds__(1024) void scan_kernel(
    const int* __restrict__ cnt, int* __restrict__ row, int n) {
  __shared__ int wtot[16];
  __shared__ int carry_s;
  const int tid = threadIdx.x;
  const int lane = tid & 63, wv = tid >> 6;
  if (tid == 0) { carry_s = 0; row[0] = 0; }
  __syncthreads();
  for (int base = 0; base < n; base += 8192) {
    const int i0 = base + tid * 8;
    int v, sacc[8];
    int run = 0;
#pragma unroll
    for (int k = 0; k < 8; k++) {
      v = (i0 + k < n) ? cnt[i0 + k] : 0;
      run += v;
      sacc[k] = run;
    }
    int x = run;
#pragma unroll
    for (int off = 1; off < 64; off <<= 1) {
      const int y = __shfl_up(x, off);
      if (lane >= off) x += y;
    }
    if (lane == 63) wtot[wv] = x;
    __syncthreads();
    int woff = 0;
#pragma unroll
    for (int k = 0; k < 16; k++) woff += (k < wv) ? wtot[k] : 0;
    const int thr_excl = (x - run) + woff + carry_s;
#pragma unroll
    for (int k = 0; k < 8; k++)
      if (i0 + k < n) row[i0 + k + 1] = thr_excl + sacc[k];
    __syncthreads();
    if (tid == 1023) carry_s = thr_excl + run;
    __syncthreads();
  }
}

__global__ __launch_bounds__(256) void scatter2_kernel(
    const int* __restrict__ src, const int* __restrict__ dst,
    const int* __restrict__ PH, const int* __restrict__ rowU,
    const int* __restrict__ rowI, int* __restrict__ adjU,
    int* __restrict__ adjI) {
  __shared__ int pos[HSLOTS];
  const int p = blockIdx.x & (P_PART - 1);
  const int s = blockIdx.x >> 4;
  const int uLo = p * U_LOC, iLo = p * I_LOC;
  const int* pre = PH + (size_t)blockIdx.x * HSLOTS;
  for (int i = threadIdx.x; i < U_LOC; i += 256)
    pos[i] = rowU[uLo + i] + pre[i];
  for (int i = threadIdx.x; i < I_LOC; i += 256)
    pos[U_LOC + i] = rowI[iLo + i] + pre[U_LOC + i];
  __syncthreads();
  const int e0 = s * E_SLICE;
  const int4* s4 = reinterpret_cast<const int4*>(src + e0);
  const int4* d4 = reinterpret_cast<const int4*>(dst + e0);
  for (int i = threadIdx.x; i < Q_SLICE; i += 256) {
    const int4 us = s4[i];
    const int4 ds = d4[i];
#pragma unroll
    for (int q = 0; q < 4; q++) {
      const int u  = (q == 0) ? us.x : (q == 1) ? us.y : (q == 2) ? us.z : us.w;
      const int it = (q == 0) ? ds.x : (q == 1) ? ds.y : (q == 2) ? ds.z : ds.w;
      const int ul = u - uLo, il = it - iLo;
      if ((unsigned)ul < (unsigned)U_LOC) {
        const int pp = atomicAdd(&pos[ul], 1);
        adjU[pp] = it;
      }
      if ((unsigned)il < (unsigned)I_LOC) {
        const int pp = atomicAdd(&pos[U_LOC + il], 1);
        adjI[pp] = u;
      }
    }
  }
}

// ---------------- aggregations on bf16 features (8-deep unroll) ----------------
__global__ __launch_bounds__(256) void agg_max_kernel(
    const unsigned short* __restrict__ feat, const int* __restrict__ rowptr,
    const int* __restrict__ adj, unsigned short* __restrict__ out, int nseg) {
  const int lane = threadIdx.x & 63;
  const int wid  = rfl((int)(threadIdx.x >> 6));
  for (int s = blockIdx.x * 4 + wid; s < nseg; s += gridDim.x * 4) {
    const int beg = rowptr[s], end = rowptr[s + 1];
    float m0 = -INFINITY, m1 = -INFINITY, m2 = -INFINITY, m3 = -INFINITY;
    float m4 = -INFINITY, m5 = -INFINITY, m6 = -INFINITY, m7 = -INFINITY;
    int j = beg;
    for (; j + 8 <= end; j += 8) {
      m0 = fmaxf(m0, bf2f(feat[(size_t)adj[j + 0] * H + lane]));
      m1 = fmaxf(m1, bf2f(feat[(size_t)adj[j + 1] * H + lane]));
      m2 = fmaxf(m2, bf2f(feat[(size_t)adj[j + 2] * H + lane]));
      m3 = fmaxf(m3, bf2f(feat[(size_t)adj[j + 3] * H + lane]));
      m4 = fmaxf(m4, bf2f(feat[(size_t)adj[j + 4] * H + lane]));
      m5 = fmaxf(m5, bf2f(feat[(size_t)adj[j + 5] * H + lane]));
      m6 = fmaxf(m6, bf2f(feat[(size_t)adj[j + 6] * H + lane]));
      m7 = fmaxf(m7, bf2f(feat[(size_t)adj[j + 7] * H + lane]));
    }
    for (; j < end; j++) m0 = fmaxf(m0, bf2f(feat[(size_t)adj[j] * H + lane]));
    const float m = fmaxf(fmaxf(fmaxf(m0, m1), fmaxf(m2, m3)),
                          fmaxf(fmaxf(m4, m5), fmaxf(m6, m7)));
    out[(size_t)s * H + lane] = (end > beg) ? f2bf(m) : (unsigned short)0;
  }
}

__global__ __launch_bounds__(256) void agg_mean_kernel(
    const unsigned short* __restrict__ feat, const int* __restrict__ rowptr,
    const int* __restrict__ adj, unsigned short* __restrict__ out, int nseg) {
  const int lane = threadIdx.x & 63;
  const int wid  = rfl((int)(threadIdx.x >> 6));
  for (int s = blockIdx.x * 4 + wid; s < nseg; s += gridDim.x * 4) {
    const int beg = rowptr[s], end = rowptr[s + 1];
    float a0 = 0.f, a1 = 0.f, a2 = 0.f, a3 = 0.f;
    float a4 = 0.f, a5 = 0.f, a6 = 0.f, a7 = 0.f;
    int j = beg;
    for (; j + 8 <= end; j += 8) {
      a0 += bf2f(feat[(size_t)adj[j + 0] * H + lane]);
      a1 += bf2f(feat[(size_t)adj[j + 1] * H + lane]);
      a2 += bf2f(feat[(size_t)adj[j + 2] * H + lane]);
      a3 += bf2f(feat[(size_t)adj[j + 3] * H + lane]);
      a4 += bf2f(feat[(size_t)adj[j + 4] * H + lane]);
      a5 += bf2f(feat[(size_t)adj[j + 5] * H + lane]);
      a6 += bf2f(feat[(size_t)adj[j + 6] * H + lane]);
      a7 += bf2f(feat[(size_t)adj[j + 7] * H + lane]);
    }
    for (; j < end; j++) a0 += bf2f(feat[(size_t)adj[j] * H + lane]);
    const float inv = 1.f / (float)((end - beg) > 1 ? (end - beg) : 1);
    out[(size_t)s * H + lane] =
        f2bf((((a0 + a1) + (a2 + a3)) + ((a4 + a5) + (a6 + a7))) * inv);
  }
}

// ---------------- head via MFMA: 16 edges/wave ----------------
// fc1 = mfma over K=128 (A = gathered [uh|ih] rows, B = packed fc1 table);
// relu+fc2 in-register; 4-step shfl_xor reduce over the 16-lane column group.
__global__ __launch_bounds__(256) void head_mfma(
    const unsigned short* __restrict__ ux, const unsigned short* __restrict__ ix,
    const int* __restrict__ eliU, const int* __restrict__ eliI,
    const unsigned short* __restrict__ W1f, const float* __restrict__ b1,
    const float* __restrict__ W2, const float* __restrict__ b2,
    float* __restrict__ out) {
  const int lane = threadIdx.x & 63;
  const int wave = rfl((int)(threadIdx.x >> 6));
  const int r0 = (blockIdx.x * 4 + wave) * 16;
  if (r0 >= NB) return;
  const int rr = r0 + (lane & 15);
  const int rc = rr < NB ? rr : NB - 1;
  const int idxU = eliU[rc], idxI = eliI[rc];
  const int k0 = (lane >> 4) * 8;
  f32x4 acc[4] = {};
#pragma unroll
  for (int ks = 0; ks < 4; ks++) {
    const unsigned short* ap = (ks < 2)
        ? ux + (size_t)idxU * 64 + (ks & 1) * 32 + k0
        : ix + (size_t)idxI * 64 + (ks & 1) * 32 + k0;
    const bf16x8 af = *reinterpret_cast<const bf16x8*>(ap);
#pragma unroll
    for (int ct = 0; ct < 4; ct++) {
      const bf16x8 bfr = *reinterpret_cast<const bf16x8*>(
          W1f + ((size_t)(ks * 4 + ct) * 64 + lane) * 8);
      acc[ct] = __builtin_amdgcn_mfma_f32_16x16x32_bf16(af, bfr, acc[ct], 0, 0, 0);
    }
  }
  float p[4][4];
#pragma unroll
  for (int i = 0; i < 4; i++)
#pragma unroll
    for (int o = 0; o < 4; o++) p[i][o] = 0.f;
#pragma unroll
  for (int ct = 0; ct < 4; ct++) {
    const int col = ct * 16 + (lane & 15);
    const float bb = b1[col];
    const float wa = W2[col * 4 + 0], wb = W2[col * 4 + 1];
    const float wc = W2[col * 4 + 2], wd = W2[col * 4 + 3];
#pragma unroll
    for (int i = 0; i < 4; i++) {
      const float h = fmaxf(acc[ct][i] + bb, 0.f);
      p[i][0] = fmaf(h, wa, p[i][0]);
      p[i][1] = fmaf(h, wb, p[i][1]);
      p[i][2] = fmaf(h, wc, p[i][2]);
      p[i][3] = fmaf(h, wd, p[i][3]);
    }
  }
#pragma unroll
  for (int off = 1; off < 16; off <<= 1) {
#pragma unroll
    for (int i = 0; i < 4; i++) {
      p[i][0] += __shfl_xor(p[i][0], off);
      p[i][1] += __shfl_xor(p[i][1], off);
      p[i][2] += __shfl_xor(p[i][2], off);
      p[i][3] += __shfl_xor(p[i][3], off);
    }
  }
  if ((lane & 15) == 0) {
    const int row0 = r0 + (lane >> 4) * 4;
#pragma unroll
    for (int i = 0; i < 4; i++) {
      const int r = row0 + i;
      if (r < NB) {
        float4 o4 = { p[i][0] + b2[0], p[i][1] + b2[1],
                      p[i][2] + b2[2], p[i][3] + b2[3] };
        *reinterpret_cast<float4*>(out + (size_t)r * 4) = o4;
      }
    }
  }
}

// ---------------- launch ----------------
extern "C" void kernel_launch(void* const* d_in, const int* in_sizes, int n_in,
                              void* d_out, int out_size, void* d_ws, size_t ws_size,
                              hipStream_t stream) {
  const float* userF = (const float*)d_in[0];
  const float* itemF = (const float*)d_in[1];
  const int*   src   = (const int*)d_in[2];
  const int*   dst   = src + NE;
  const int*   eliU  = (const int*)d_in[3];
  const int*   eliI  = eliU + NB;
  const float* upW = (const float*)d_in[4],  *upb = (const float*)d_in[5];
  const float* ipW = (const float*)d_in[6],  *ipb = (const float*)d_in[7];
  const float* ulW = (const float*)d_in[8],  *ulb = (const float*)d_in[9];
  const float* urW = (const float*)d_in[10];
  const float* ilW = (const float*)d_in[11], *ilb = (const float*)d_in[12];
  const float* irW = (const float*)d_in[13];
  const float* ug  = (const float*)d_in[14], *ube = (const float*)d_in[15];
  const float* um  = (const float*)d_in[16], *uv  = (const float*)d_in[17];
  const float* ig  = (const float*)d_in[18], *ibe = (const float*)d_in[19];
  const float* im  = (const float*)d_in[20], *iv  = (const float*)d_in[21];
  const float* f1W = (const float*)d_in[22], *f1b = (const float*)d_in[23];
  const float* f2W = (const float*)d_in[24], *f2b = (const float*)d_in[25];
  float* outp = (float*)d_out;

  char* p = (char*)d_ws;
  auto alloc = [&](size_t bytes) {
    char* r = p;
    p += (bytes + 255) & ~(size_t)255;
    return r;
  };
  unsigned short* ux0 = (unsigned short*)alloc((size_t)N_USERS * H * 2);
  unsigned short* ix0 = (unsigned short*)alloc((size_t)N_ITEMS * H * 2);
  char* grp = alloc((size_t)38400 * 1024);
  unsigned short* agU = (unsigned short*)grp;
  unsigned short* agI = agU + (size_t)N_USERS * H;
  unsigned short* ux1 = agI + (size_t)N_ITEMS * H;
  unsigned short* ix1 = ux1 + (size_t)N_USERS * H;
  int* PH = (int*)grp;  // 800 x 9375 ints = 30 MB
  int*   rowU = (int*)alloc((size_t)(N_USERS + 1) * 4);
  int*   rowI = (int*)alloc((size_t)(N_ITEMS + 1) * 4);
  int*   cntU = (int*)alloc((size_t)N_USERS * 4);
  int*   cntI = (int*)alloc((size_t)N_ITEMS * 4);
  int*   adjU = (int*)alloc((size_t)NE * 4);
  int*   adjI = (int*)alloc((size_t)NE * 4);
  unsigned short* wpack = (unsigned short*)alloc((size_t)32 * 2048 * 2);  // 256 KB

  const int G = 2048, T = 256;
  pack_kernel<<<32, T, 0, stream>>>(upW, ipW, ulW, urW, ilW, irW, f1W, wpack);
  proj_mfma<256><<<(N_USERS + 63) / 64, T, 0, stream>>>(userF, wpack, upb, ux0, N_USERS);
  proj_mfma<128><<<(N_ITEMS + 63) / 64, T, 0, stream>>>(itemF, wpack + 8 * 2048, ipb, ix0, N_ITEMS);
  hist2_kernel<<<NBLK_CSR, T, 0, stream>>>(src, dst, PH);
  combine_kernel<<<(P_PART * HSLOTS + 255) / 256, T, 0, stream>>>(PH, cntU, cntI);
  scan_kernel<<<1, 1024, 0, stream>>>(cntU, rowU, N_USERS);
  scan_kernel<<<1, 1024, 0, stream>>>(cntI, rowI, N_ITEMS);
  scatter2_kernel<<<NBLK_CSR, T, 0, stream>>>(src, dst, PH, rowU, rowI, adjU, adjI);

  const unsigned short* uin = ux0;
  const unsigned short* iin = ix0;
  unsigned short* uout = ux1;
  unsigned short* iout = ix1;
  const int GU = (N_USERS + 63) / 64, GI = (N_ITEMS + 63) / 64;
  for (int l = 0; l < 2; l++) {
    unsigned short* cwU = wpack + (12 + 4 * (0 + l)) * 2048;
    unsigned short* cwI = wpack + (12 + 4 * (2 + l)) * 2048;
    agg_max_kernel<<<G, T, 0, stream>>>(iin, rowU, adjU, agU, N_USERS);
    conv_mfma<<<GU, T, 0, stream>>>(agU, uin, cwU, ulb + l * 64,
                                    ug + l * 64, ube + l * 64,
                                    um + l * 64, uv + l * 64, uout, N_USERS);
    agg_mean_kernel<<<G, T, 0, stream>>>(uin, rowI, adjI, agI, N_ITEMS);
    conv_mfma<<<GI, T, 0, stream>>>(agI, iin, cwI, ilb + l * 64,
                                    ig + l * 64, ibe + l * 64,
                                    im + l * 64, iv + l * 64, iout, N_ITEMS);
    const unsigned short* t;
    t = uin; uin = uout; uout = (unsigned short*)t;
    t = iin; iin = iout; iout = (unsigned short*)t;
  }
  head_mfma<<<(NB / 16 + 3) / 4, T, 0, stream>>>(uin, iin, eliU, eliI,
                                                 wpack + 28 * 2048, f1b, f2W, f2b, outp);
}

// Round 10
// 378.701 us; speedup vs baseline: 2.6465x; 1.3366x over previous
//
#include <hip/hip_runtime.h>
#include <math.h>

#define N_USERS 100000
#define N_ITEMS 50000
#define NE      2000000
#define NB      100000
#define H       64
#define BN_EPS  1e-5f
#define P_PART  16                         // node partitions (2 per XCD)
#define U_LOC   (N_USERS / P_PART)         // 6250
#define I_LOC   (N_ITEMS / P_PART)         // 3125
#define HSLOTS  (U_LOC + I_LOC)            // 9375 ints = 37.5 KB LDS
#define S_SLICES 50
#define NBLK_CSR (P_PART * S_SLICES)       // 800
#define E_SLICE  (NE / S_SLICES)           // 40000 (mult of 4, 16B-aligned)
#define Q_SLICE  (E_SLICE / 4)             // 10000 int4 quads
#define SCAN_CHUNK 2048                    // elems per scan block (256 thr x 8)

typedef __attribute__((ext_vector_type(8))) short bf16x8;
typedef __attribute__((ext_vector_type(4))) float f32x4;

static __device__ __forceinline__ int rfl(int x) { return __builtin_amdgcn_readfirstlane(x); }

static __device__ __forceinline__ unsigned short f2bf(float f) {   // RTNE
  union { float f; unsigned u; } v; v.f = f;
  const unsigned r = v.u + 0x7fffu + ((v.u >> 16) & 1u);
  return (unsigned short)(r >> 16);
}
static __device__ __forceinline__ float bf2f(unsigned short h) {
  union { unsigned u; float f; } v; v.u = (unsigned)h << 16;
  return v.f;
}

// ---------------- weight pre-pack into MFMA fragment order ----------------
// blocks 0..7: user proj (K=256); 8..11: item proj (K=128);
// 12..27: conv tables; 28..31: fc1 head (K=128).
__global__ __launch_bounds__(256) void pack_kernel(
    const float* __restrict__ upW, const float* __restrict__ ipW,
    const float* __restrict__ ulW, const float* __restrict__ urW,
    const float* __restrict__ ilW, const float* __restrict__ irW,
    const float* __restrict__ f1W, unsigned short* __restrict__ dst) {
  const int b = blockIdx.x;
  const int ct = threadIdx.x >> 6, lane = threadIdx.x & 63;
  const float* src;
  int krow0;
  if (b < 8)       { src = upW; krow0 = b * 32; }
  else if (b < 12) { src = ipW; krow0 = (b - 8) * 32; }
  else if (b < 28) {
    const int idx = b - 12, t = idx >> 2, ks = idx & 3;
    const int layer = t & 1;
    const float* Wl = (t < 2) ? ulW : ilW;
    const float* Wr = (t < 2) ? urW : irW;
    src = ((ks < 2) ? Wl : Wr) + layer * 4096;
    krow0 = ((ks < 2) ? ks : ks - 2) * 32;
  } else { src = f1W; krow0 = (b - 28) * 32; }
  unsigned short* out = dst + (size_t)b * 2048 + ((size_t)ct * 64 + lane) * 8;
  const int col = ct * 16 + (lane & 15);
  const int kr = krow0 + (lane >> 4) * 8;
#pragma unroll
  for (int j = 0; j < 8; j++) out[j] = f2bf(src[(kr + j) * 64 + col]);
}

// ---------------- proj: Y[N,64] = bf16(X[N,K] @ W + b) via MFMA ----------------
template<int K>
__global__ __launch_bounds__(256) void proj_mfma(
    const float* __restrict__ X, const unsigned short* __restrict__ Wf,
    const float* __restrict__ bias, unsigned short* __restrict__ Y, int nrows) {
  const int lane = threadIdx.x & 63;
  const int wave = rfl((int)(threadIdx.x >> 6));
  const int r0 = (blockIdx.x * 4 + wave) * 16;
  if (r0 >= nrows) return;
  const int arow = r0 + (lane & 15);
  const int ar = arow < nrows ? arow : nrows - 1;
  const int k0 = (lane >> 4) * 8;
  f32x4 acc[4] = {};
#pragma unroll
  for (int ks = 0; ks < K / 32; ks++) {
    const float* xp = X + (size_t)ar * K + ks * 32 + k0;
    const float4 xa = *reinterpret_cast<const float4*>(xp);
    const float4 xb = *reinterpret_cast<const float4*>(xp + 4);
    bf16x8 af;
    af[0] = f2bf(xa.x); af[1] = f2bf(xa.y); af[2] = f2bf(xa.z); af[3] = f2bf(xa.w);
    af[4] = f2bf(xb.x); af[5] = f2bf(xb.y); af[6] = f2bf(xb.z); af[7] = f2bf(xb.w);
#pragma unroll
    for (int ct = 0; ct < 4; ct++) {
      const bf16x8 bfr = *reinterpret_cast<const bf16x8*>(
          Wf + ((size_t)(ks * 4 + ct) * 64 + lane) * 8);
      acc[ct] = __builtin_amdgcn_mfma_f32_16x16x32_bf16(af, bfr, acc[ct], 0, 0, 0);
    }
  }
  const int orow0 = r0 + (lane >> 4) * 4;
#pragma unroll
  for (int ct = 0; ct < 4; ct++) {
    const int col = ct * 16 + (lane & 15);
    const float bv = bias[col];
#pragma unroll
    for (int i = 0; i < 4; i++) {
      const int r = orow0 + i;
      if (r < nrows) Y[(size_t)r * 64 + col] = f2bf(acc[ct][i] + bv);
    }
  }
}

// ---------------- conv: Y = bf16(relu(BN([AGG|XS] @ [Wl;Wr] + bl))) ----------------
__global__ __launch_bounds__(256) void conv_mfma(
    const unsigned short* __restrict__ AGG, const unsigned short* __restrict__ XS,
    const unsigned short* __restrict__ Wf, const float* __restrict__ bl,
    const float* __restrict__ gm, const float* __restrict__ bt,
    const float* __restrict__ mu, const float* __restrict__ vr,
    unsigned short* __restrict__ Y, int nrows) {
  const int lane = threadIdx.x & 63;
  const int wave = rfl((int)(threadIdx.x >> 6));
  const int r0 = (blockIdx.x * 4 + wave) * 16;
  if (r0 >= nrows) return;
  const int arow = r0 + (lane & 15);
  const int ar = arow < nrows ? arow : nrows - 1;
  const int k0 = (lane >> 4) * 8;
  f32x4 acc[4] = {};
#pragma unroll
  for (int ks = 0; ks < 4; ks++) {
    const unsigned short* ap =
        (ks < 2 ? AGG : XS) + (size_t)ar * 64 + (ks & 1) * 32 + k0;
    const bf16x8 af = *reinterpret_cast<const bf16x8*>(ap);
#pragma unroll
    for (int ct = 0; ct < 4; ct++) {
      const bf16x8 bfr = *reinterpret_cast<const bf16x8*>(
          Wf + ((size_t)(ks * 4 + ct) * 64 + lane) * 8);
      acc[ct] = __builtin_amdgcn_mfma_f32_16x16x32_bf16(af, bfr, acc[ct], 0, 0, 0);
    }
  }
  const int orow0 = r0 + (lane >> 4) * 4;
#pragma unroll
  for (int ct = 0; ct < 4; ct++) {
    const int col = ct * 16 + (lane & 15);
    const float s = gm[col] * rsqrtf(vr[col] + BN_EPS);
    const float C = (bl[col] - mu[col]) * s + bt[col];
#pragma unroll
    for (int i = 0; i < 4; i++) {
      const int r = orow0 + i;
      if (r < nrows)
        Y[(size_t)r * 64 + col] = f2bf(fmaxf(fmaf(acc[ct][i], s, C), 0.f));
    }
  }
}

// ---------------- CSR build: P=16 partitions, int4 edge loads ----------------
__global__ __launch_bounds__(256) void hist2_kernel(
    const int* __restrict__ src, const int* __restrict__ dst,
    int* __restrict__ PH) {
  __shared__ int h[HSLOTS];
  const int p = blockIdx.x & (P_PART - 1);
  const int s = blockIdx.x >> 4;
  for (int i = threadIdx.x; i < HSLOTS; i += 256) h[i] = 0;
  __syncthreads();
  const int uLo = p * U_LOC, iLo = p * I_LOC;
  const int e0 = s * E_SLICE;
  const int4* s4 = reinterpret_cast<const int4*>(src + e0);
  const int4* d4 = reinterpret_cast<const int4*>(dst + e0);
  for (int i = threadIdx.x; i < Q_SLICE; i += 256) {
    const int4 us = s4[i];
    const int4 ds = d4[i];
    int ul, il;
    ul = us.x - uLo; if ((unsigned)ul < (unsigned)U_LOC) atomicAdd(&h[ul], 1);
    ul = us.y - uLo; if ((unsigned)ul < (unsigned)U_LOC) atomicAdd(&h[ul], 1);
    ul = us.z - uLo; if ((unsigned)ul < (unsigned)U_LOC) atomicAdd(&h[ul], 1);
    ul = us.w - uLo; if ((unsigned)ul < (unsigned)U_LOC) atomicAdd(&h[ul], 1);
    il = ds.x - iLo; if ((unsigned)il < (unsigned)I_LOC) atomicAdd(&h[U_LOC + il], 1);
    il = ds.y - iLo; if ((unsigned)il < (unsigned)I_LOC) atomicAdd(&h[U_LOC + il], 1);
    il = ds.z - iLo; if ((unsigned)il < (unsigned)I_LOC) atomicAdd(&h[U_LOC + il], 1);
    il = ds.w - iLo; if ((unsigned)il < (unsigned)I_LOC) atomicAdd(&h[U_LOC + il], 1);
  }
  __syncthreads();
  int* out = PH + (size_t)blockIdx.x * HSLOTS;
  for (int i = threadIdx.x; i < HSLOTS; i += 256) out[i] = h[i];
}

__global__ __launch_bounds__(256) void combine_kernel(
    int* __restrict__ PH, int* __restrict__ cntU, int* __restrict__ cntI) {
  const int g = blockIdx.x * 256 + threadIdx.x;
  if (g >= P_PART * HSLOTS) return;
  const int x = g / HSLOTS;
  const int n = g - x * HSLOTS;
  int* p = PH + (size_t)x * HSLOTS + n;
  int run = 0;
#pragma unroll 2
  for (int s = 0; s < S_SLICES; s++) {
    int* q = p + (size_t)s * (P_PART * HSLOTS);
    const int v = *q;
    *q = run;
    run += v;
  }
  if (n < U_LOC) cntU[x * U_LOC + n] = run;
  else           cntI[x * I_LOC + (n - U_LOC)] = run;
}

// ---------------- two-level parallel exclusive scan ----------------
// scan1: each block scans its 2048-elem chunk locally; writes row[i+1]
// (local prefix) and its block total to bsum[b].
__global__ __launch_bounds__(256) void scan1_kernel(
    const int* __restrict__ cnt, int* __restrict__ row,
    int* __restrict__ bsum, int n) {
  __shared__ int wtot[4];
  const int tid = threadIdx.x;
  const int lane = tid & 63, wv = tid >> 6;
  const int i0 = blockIdx.x * SCAN_CHUNK + tid * 8;
  int sacc[8];
  int run = 0;
#pragma unroll
  for (int k = 0; k < 8; k++) {
    const int v = (i0 + k < n) ? cnt[i0 + k] : 0;
    run += v;
    sacc[k] = run;
  }
  int x = run;
#pragma unroll
  for (int off = 1; off < 64; off <<= 1) {
    const int y = __shfl_up(x, off);
    if (lane >= off) x += y;
  }
  if (lane == 63) wtot[wv] = x;
  __syncthreads();
  int woff = 0;
#pragma unroll
  for (int k = 0; k < 4; k++) woff += (k < wv) ? wtot[k] : 0;
  const int excl = (x - run) + woff;
#pragma unroll
  for (int k = 0; k < 8; k++)
    if (i0 + k < n) row[i0 + k + 1] = excl + sacc[k];
  if (tid == 255) bsum[blockIdx.x] = excl + run;
}

// scan3: block b sums bsum[0..b-1] with one wave (nblocks <= 64), adds the
// offset to its chunk's row entries. Block 0 writes row[0]=0.
__global__ __launch_bounds__(256) void scan3_kernel(
    const int* __restrict__ bsum, int* __restrict__ row, int n) {
  __shared__ int off_s;
  const int b = blockIdx.x;
  const int tid = threadIdx.x;
  if (tid < 64) {
    int v = (tid < b) ? bsum[tid] : 0;
#pragma unroll
    for (int off = 32; off; off >>= 1) v += __shfl_xor(v, off);
    if (tid == 0) off_s = v;
  }
  __syncthreads();
  const int off = off_s;
  if (b == 0) {
    if (tid == 0) row[0] = 0;
    return;  // offset is 0 for block 0
  }
  const int i0 = b * SCAN_CHUNK + tid * 8;
#pragma unroll
  for (int k = 0; k < 8; k++)
    if (i0 + k < n) row[i0 + k + 1] += off;
}

__global__ __launch_bounds__(256) void scatter2_kernel(
    const int* __restrict__ src, const int* __restrict__ dst,
    const int* __restrict__ PH, const int* __restrict__ rowU,
    const int* __restrict__ rowI, int* __restrict__ adjU,
    int* __restrict__ adjI) {
  __shared__ int pos[HSLOTS];
  const int p = blockIdx.x & (P_PART - 1);
  const int s = blockIdx.x >> 4;
  const int uLo = p * U_LOC, iLo = p * I_LOC;
  const int* pre = PH + (size_t)blockIdx.x * HSLOTS;
  for (int i = threadIdx.x; i < U_LOC; i += 256)
    pos[i] = rowU[uLo + i] + pre[i];
  for (int i = threadIdx.x; i < I_LOC; i += 256)
    pos[U_LOC + i] = rowI[iLo + i] + pre[U_LOC + i];
  __syncthreads();
  const int e0 = s * E_SLICE;
  const int4* s4 = reinterpret_cast<const int4*>(src + e0);
  const int4* d4 = reinterpret_cast<const int4*>(dst + e0);
  for (int i = threadIdx.x; i < Q_SLICE; i += 256) {
    const int4 us = s4[i];
    const int4 ds = d4[i];
#pragma unroll
    for (int q = 0; q < 4; q++) {
      const int u  = (q == 0) ? us.x : (q == 1) ? us.y : (q == 2) ? us.z : us.w;
      const int it = (q == 0) ? ds.x : (q == 1) ? ds.y : (q == 2) ? ds.z : ds.w;
      const int ul = u - uLo, il = it - iLo;
      if ((unsigned)ul < (unsigned)U_LOC) {
        const int pp = atomicAdd(&pos[ul], 1);
        adjU[pp] = it;
      }
      if ((unsigned)il < (unsigned)I_LOC) {
        const int pp = atomicAdd(&pos[U_LOC + il], 1);
        adjI[pp] = u;
      }
    }
  }
}

// ---------------- aggregations on bf16 features (8-deep unroll) ----------------
__global__ __launch_bounds__(256) void agg_max_kernel(
    const unsigned short* __restrict__ feat, const int* __restrict__ rowptr,
    const int* __restrict__ adj, unsigned short* __restrict__ out, int nseg) {
  const int lane = threadIdx.x & 63;
  const int wid  = rfl((int)(threadIdx.x >> 6));
  for (int s = blockIdx.x * 4 + wid; s < nseg; s += gridDim.x * 4) {
    const int beg = rowptr[s], end = rowptr[s + 1];
    float m0 = -INFINITY, m1 = -INFINITY, m2 = -INFINITY, m3 = -INFINITY;
    float m4 = -INFINITY, m5 = -INFINITY, m6 = -INFINITY, m7 = -INFINITY;
    int j = beg;
    for (; j + 8 <= end; j += 8) {
      m0 = fmaxf(m0, bf2f(feat[(size_t)adj[j + 0] * H + lane]));
      m1 = fmaxf(m1, bf2f(feat[(size_t)adj[j + 1] * H + lane]));
      m2 = fmaxf(m2, bf2f(feat[(size_t)adj[j + 2] * H + lane]));
      m3 = fmaxf(m3, bf2f(feat[(size_t)adj[j + 3] * H + lane]));
      m4 = fmaxf(m4, bf2f(feat[(size_t)adj[j + 4] * H + lane]));
      m5 = fmaxf(m5, bf2f(feat[(size_t)adj[j + 5] * H + lane]));
      m6 = fmaxf(m6, bf2f(feat[(size_t)adj[j + 6] * H + lane]));
      m7 = fmaxf(m7, bf2f(feat[(size_t)adj[j + 7] * H + lane]));
    }
    for (; j < end; j++) m0 = fmaxf(m0, bf2f(feat[(size_t)adj[j] * H + lane]));
    const float m = fmaxf(fmaxf(fmaxf(m0, m1), fmaxf(m2, m3)),
                          fmaxf(fmaxf(m4, m5), fmaxf(m6, m7)));
    out[(size_t)s * H + lane] = (end > beg) ? f2bf(m) : (unsigned short)0;
  }
}

__global__ __launch_bounds__(256) void agg_mean_kernel(
    const unsigned short* __restrict__ feat, const int* __restrict__ rowptr,
    const int* __restrict__ adj, unsigned short* __restrict__ out, int nseg) {
  const int lane = threadIdx.x & 63;
  const int wid  = rfl((int)(threadIdx.x >> 6));
  for (int s = blockIdx.x * 4 + wid; s < nseg; s += gridDim.x * 4) {
    const int beg = rowptr[s], end = rowptr[s + 1];
    float a0 = 0.f, a1 = 0.f, a2 = 0.f, a3 = 0.f;
    float a4 = 0.f, a5 = 0.f, a6 = 0.f, a7 = 0.f;
    int j = beg;
    for (; j + 8 <= end; j += 8) {
      a0 += bf2f(feat[(size_t)adj[j + 0] * H + lane]);
      a1 += bf2f(feat[(size_t)adj[j + 1] * H + lane]);
      a2 += bf2f(feat[(size_t)adj[j + 2] * H + lane]);
      a3 += bf2f(feat[(size_t)adj[j + 3] * H + lane]);
      a4 += bf2f(feat[(size_t)adj[j + 4] * H + lane]);
      a5 += bf2f(feat[(size_t)adj[j + 5] * H + lane]);
      a6 += bf2f(feat[(size_t)adj[j + 6] * H + lane]);
      a7 += bf2f(feat[(size_t)adj[j + 7] * H + lane]);
    }
    for (; j < end; j++) a0 += bf2f(feat[(size_t)adj[j] * H + lane]);
    const float inv = 1.f / (float)((end - beg) > 1 ? (end - beg) : 1);
    out[(size_t)s * H + lane] =
        f2bf((((a0 + a1) + (a2 + a3)) + ((a4 + a5) + (a6 + a7))) * inv);
  }
}

// ---------------- head via MFMA: 16 edges/wave ----------------
__global__ __launch_bounds__(256) void head_mfma(
    const unsigned short* __restrict__ ux, const unsigned short* __restrict__ ix,
    const int* __restrict__ eliU, const int* __restrict__ eliI,
    const unsigned short* __restrict__ W1f, const float* __restrict__ b1,
    const float* __restrict__ W2, const float* __restrict__ b2,
    float* __restrict__ out) {
  const int lane = threadIdx.x & 63;
  const int wave = rfl((int)(threadIdx.x >> 6));
  const int r0 = (blockIdx.x * 4 + wave) * 16;
  if (r0 >= NB) return;
  const int rr = r0 + (lane & 15);
  const int rc = rr < NB ? rr : NB - 1;
  const int idxU = eliU[rc], idxI = eliI[rc];
  const int k0 = (lane >> 4) * 8;
  f32x4 acc[4] = {};
#pragma unroll
  for (int ks = 0; ks < 4; ks++) {
    const unsigned short* ap = (ks < 2)
        ? ux + (size_t)idxU * 64 + (ks & 1) * 32 + k0
        : ix + (size_t)idxI * 64 + (ks & 1) * 32 + k0;
    const bf16x8 af = *reinterpret_cast<const bf16x8*>(ap);
#pragma unroll
    for (int ct = 0; ct < 4; ct++) {
      const bf16x8 bfr = *reinterpret_cast<const bf16x8*>(
          W1f + ((size_t)(ks * 4 + ct) * 64 + lane) * 8);
      acc[ct] = __builtin_amdgcn_mfma_f32_16x16x32_bf16(af, bfr, acc[ct], 0, 0, 0);
    }
  }
  float p[4][4];
#pragma unroll
  for (int i = 0; i < 4; i++)
#pragma unroll
    for (int o = 0; o < 4; o++) p[i][o] = 0.f;
#pragma unroll
  for (int ct = 0; ct < 4; ct++) {
    const int col = ct * 16 + (lane & 15);
    const float bb = b1[col];
    const float wa = W2[col * 4 + 0], wb = W2[col * 4 + 1];
    const float wc = W2[col * 4 + 2], wd = W2[col * 4 + 3];
#pragma unroll
    for (int i = 0; i < 4; i++) {
      const float h = fmaxf(acc[ct][i] + bb, 0.f);
      p[i][0] = fmaf(h, wa, p[i][0]);
      p[i][1] = fmaf(h, wb, p[i][1]);
      p[i][2] = fmaf(h, wc, p[i][2]);
      p[i][3] = fmaf(h, wd, p[i][3]);
    }
  }
#pragma unroll
  for (int off = 1; off < 16; off <<= 1) {
#pragma unroll
    for (int i = 0; i < 4; i++) {
      p[i][0] += __shfl_xor(p[i][0], off);
      p[i][1] += __shfl_xor(p[i][1], off);
      p[i][2] += __shfl_xor(p[i][2], off);
      p[i][3] += __shfl_xor(p[i][3], off);
    }
  }
  if ((lane & 15) == 0) {
    const int row0 = r0 + (lane >> 4) * 4;
#pragma unroll
    for (int i = 0; i < 4; i++) {
      const int r = row0 + i;
      if (r < NB) {
        float4 o4 = { p[i][0] + b2[0], p[i][1] + b2[1],
                      p[i][2] + b2[2], p[i][3] + b2[3] };
        *reinterpret_cast<float4*>(out + (size_t)r * 4) = o4;
      }
    }
  }
}

// ---------------- launch ----------------
extern "C" void kernel_launch(void* const* d_in, const int* in_sizes, int n_in,
                              void* d_out, int out_size, void* d_ws, size_t ws_size,
                              hipStream_t stream) {
  const float* userF = (const float*)d_in[0];
  const float* itemF = (const float*)d_in[1];
  const int*   src   = (const int*)d_in[2];
  const int*   dst   = src + NE;
  const int*   eliU  = (const int*)d_in[3];
  const int*   eliI  = eliU + NB;
  const float* upW = (const float*)d_in[4],  *upb = (const float*)d_in[5];
  const float* ipW = (const float*)d_in[6],  *ipb = (const float*)d_in[7];
  const float* ulW = (const float*)d_in[8],  *ulb = (const float*)d_in[9];
  const float* urW = (const float*)d_in[10];
  const float* ilW = (const float*)d_in[11], *ilb = (const float*)d_in[12];
  const float* irW = (const float*)d_in[13];
  const float* ug  = (const float*)d_in[14], *ube = (const float*)d_in[15];
  const float* um  = (const float*)d_in[16], *uv  = (const float*)d_in[17];
  const float* ig  = (const float*)d_in[18], *ibe = (const float*)d_in[19];
  const float* im  = (const float*)d_in[20], *iv  = (const float*)d_in[21];
  const float* f1W = (const float*)d_in[22], *f1b = (const float*)d_in[23];
  const float* f2W = (const float*)d_in[24], *f2b = (const float*)d_in[25];
  float* outp = (float*)d_out;

  char* p = (char*)d_ws;
  auto alloc = [&](size_t bytes) {
    char* r = p;
    p += (bytes + 255) & ~(size_t)255;
    return r;
  };
  unsigned short* ux0 = (unsigned short*)alloc((size_t)N_USERS * H * 2);
  unsigned short* ix0 = (unsigned short*)alloc((size_t)N_ITEMS * H * 2);
  char* grp = alloc((size_t)38400 * 1024);
  unsigned short* agU = (unsigned short*)grp;
  unsigned short* agI = agU + (size_t)N_USERS * H;
  unsigned short* ux1 = agI + (size_t)N_ITEMS * H;
  unsigned short* ix1 = ux1 + (size_t)N_USERS * H;
  int* PH = (int*)grp;  // 800 x 9375 ints = 30 MB
  int*   rowU = (int*)alloc((size_t)(N_USERS + 1) * 4);
  int*   rowI = (int*)alloc((size_t)(N_ITEMS + 1) * 4);
  int*   cntU = (int*)alloc((size_t)N_USERS * 4);
  int*   cntI = (int*)alloc((size_t)N_ITEMS * 4);
  int*   adjU = (int*)alloc((size_t)NE * 4);
  int*   adjI = (int*)alloc((size_t)NE * 4);
  int*   bsumU = (int*)alloc(64 * 4);
  int*   bsumI = (int*)alloc(64 * 4);
  unsigned short* wpack = (unsigned short*)alloc((size_t)32 * 2048 * 2);  // 256 KB

  const int G = 2048, T = 256;
  const int SBU = (N_USERS + SCAN_CHUNK - 1) / SCAN_CHUNK;  // 49
  const int SBI = (N_ITEMS + SCAN_CHUNK - 1) / SCAN_CHUNK;  // 25
  pack_kernel<<<32, T, 0, stream>>>(upW, ipW, ulW, urW, ilW, irW, f1W, wpack);
  proj_mfma<256><<<(N_USERS + 63) / 64, T, 0, stream>>>(userF, wpack, upb, ux0, N_USERS);
  proj_mfma<128><<<(N_ITEMS + 63) / 64, T, 0, stream>>>(itemF, wpack + 8 * 2048, ipb, ix0, N_ITEMS);
  hist2_kernel<<<NBLK_CSR, T, 0, stream>>>(src, dst, PH);
  combine_kernel<<<(P_PART * HSLOTS + 255) / 256, T, 0, stream>>>(PH, cntU, cntI);
  scan1_kernel<<<SBU, T, 0, stream>>>(cntU, rowU, bsumU, N_USERS);
  scan1_kernel<<<SBI, T, 0, stream>>>(cntI, rowI, bsumI, N_ITEMS);
  scan3_kernel<<<SBU, T, 0, stream>>>(bsumU, rowU, N_USERS);
  scan3_kernel<<<SBI, T, 0, stream>>>(bsumI, rowI, N_ITEMS);
  scatter2_kernel<<<NBLK_CSR, T, 0, stream>>>(src, dst, PH, rowU, rowI, adjU, adjI);

  const unsigned short* uin = ux0;
  const unsigned short* iin = ix0;
  unsigned short* uout = ux1;
  unsigned short* iout = ix1;
  const int GU = (N_USERS + 63) / 64, GI = (N_ITEMS + 63) / 64;
  for (int l = 0; l < 2; l++) {
    unsigned short* cwU = wpack + (12 + 4 * (0 + l)) * 2048;
    unsigned short* cwI = wpack + (12 + 4 * (2 + l)) * 2048;
    agg_max_kernel<<<G, T, 0, stream>>>(iin, rowU, adjU, agU, N_USERS);
    conv_mfma<<<GU, T, 0, stream>>>(agU, uin, cwU, ulb + l * 64,
                                    ug + l * 64, ube + l * 64,
                                    um + l * 64, uv + l * 64, uout, N_USERS);
    agg_mean_kernel<<<G, T, 0, stream>>>(uin, rowI, adjI, agI, N_ITEMS);
    conv_mfma<<<GI, T, 0, stream>>>(agI, iin, cwI, ilb + l * 64,
                                    ig + l * 64, ibe + l * 64,
                                    im + l * 64, iv + l * 64, iout, N_ITEMS);
    const unsigned short* t;
    t = uin; uin = uout; uout = (unsigned short*)t;
    t = iin; iin = iout; iout = (unsigned short*)t;
  }
  head_mfma<<<(NB / 16 + 3) / 4, T, 0, stream>>>(uin, iin, eliU, eliI,
                                                 wpack + 28 * 2048, f1b, f2W, f2b, outp);
}